// Round 3
// baseline (716.255 us; speedup 1.0000x reference)
//
#include <hip/hip_runtime.h>
#include <hip/hip_bf16.h>

typedef __attribute__((ext_vector_type(8))) short short8;
typedef __attribute__((ext_vector_type(4))) float f32x4;

static constexpr int NN = 50000;   // nodes
static constexpr int NE = 800000;  // edges

#define MFMA16x16x32 __builtin_amdgcn_mfma_f32_16x16x32_bf16

__device__ __forceinline__ float b2f(unsigned short u){
  unsigned v = ((unsigned)u) << 16;
  return __builtin_bit_cast(float, v);
}
__device__ __forceinline__ unsigned short f2b(float f){
  unsigned x = __builtin_bit_cast(unsigned, f);
  unsigned r = (x + 0x7fffu + ((x >> 16) & 1u)) >> 16;  // RNE
  return (unsigned short)r;
}

// ---------------- static device scratch (module-load allocated; d_ws unused)
__device__ __align__(256) int   g_isf32;                     // runtime dtype flag
__device__ __align__(256) unsigned short g_X   [(size_t)NN * 512];  // staged data_x, bf16, zero-padded K 500->512
__device__ __align__(256) unsigned short g_W1t  [112 * 512];
__device__ __align__(256) unsigned short g_W2t  [112 * 128];
__device__ __align__(256) unsigned short g_WselfT[112 * 128];
__device__ __align__(256) unsigned short g_WrelT [112 * 128];
__device__ __align__(256) unsigned short g_c1Wt [112 * 128];
__device__ __align__(256) unsigned short g_c2Wt [64 * 128];
__device__ __align__(256) unsigned short g_bufA[(size_t)NN * 128];
__device__ __align__(256) unsigned short g_bufB[(size_t)NN * 128];
__device__ __align__(256) unsigned short g_bufC[(size_t)NN * 128];
__device__ __align__(256) int   g_deg[NN];
__device__ __align__(256) int   g_rowptr[NN + 1];
__device__ __align__(256) int   g_cursor[NN];
__device__ __align__(256) int   g_colidx[NE];
__device__ __align__(256) float g_dinv[NN];

// read one float-typed input element, whatever its storage dtype is
__device__ __forceinline__ float ld_in(const void* p, int idx, int isf32){
  if (isf32) return ((const float*)p)[idx];
  return b2f(((const unsigned short*)p)[idx]);
}

// ---------------- dtype sniffer: even halfwords of f32 data are uniform mantissa
// bits (~28% in exponent band); bf16 data has ~100% in band.
__global__ void k_detect(const unsigned short* __restrict__ x){
  __shared__ int sh[256];
  int tid = threadIdx.x;
  int cnt = 0;
  for (int j = 0; j < 16; j++){
    unsigned short h = x[(size_t)(tid * 16 + j) * 2];  // even halfwords
    int e = (h >> 7) & 0xFF;
    if (e >= 90 && e <= 160) cnt++;
  }
  sh[tid] = cnt;
  __syncthreads();
  for (int off = 128; off > 0; off >>= 1){
    if (tid < off) sh[tid] += sh[tid + off];
    __syncthreads();
  }
  if (tid == 0) g_isf32 = (sh[0] < 2458) ? 1 : 0;  // 60% threshold of 4096
}

// ---------------- zero deg/cursor each call
__global__ void k_zero(){
  int i = blockIdx.x * 256 + threadIdx.x;
  if (i < NN){ g_deg[i] = 0; g_cursor[i] = 0; }
}

// ---------------- stage data_x -> g_X [NN][512] bf16, zero-padded
__global__ void k_stagex(const void* __restrict__ x){
  int idx = blockIdx.x * 256 + threadIdx.x;
  if (idx >= NN * 512) return;
  int n = idx >> 9, k = idx & 511;
  unsigned short v = 0;
  if (k < 500){
    int isf32 = g_isf32;
    if (isf32) v = f2b(((const float*)x)[(size_t)n * 500 + k]);
    else       v = ((const unsigned short*)x)[(size_t)n * 500 + k];
  }
  g_X[idx] = v;
}

// ---------------- weight prep: W[K,Nc] -> Wt[Npad][Kpad], zero-padded, bf16
template<int SEL>
__global__ void k_transpose(const void* __restrict__ W){
  constexpr int K    = (SEL == 0) ? 500 : 100;
  constexpr int Nc   = (SEL == 5) ? 64  : 100;
  constexpr int Kpad = (SEL == 0) ? 512 : 128;
  constexpr int Npad = (SEL == 5) ? 64  : 112;
  unsigned short* Wt = (SEL == 0) ? g_W1t : (SEL == 1) ? g_W2t : (SEL == 2) ? g_WselfT
                     : (SEL == 3) ? g_WrelT : (SEL == 4) ? g_c1Wt : g_c2Wt;
  int idx = blockIdx.x * 256 + threadIdx.x;
  if (idx >= Kpad * Npad) return;
  int n = idx / Kpad;
  int k = idx - n * Kpad;
  float v = 0.f;
  if (n < Nc && k < K) v = ld_in(W, k * Nc + n, g_isf32);
  Wt[idx] = f2b(v);
}

// ---------------- degree histogram (in-degree by tgt)
__global__ void k_deg(const int* __restrict__ tgt){
  int e = blockIdx.x * 256 + threadIdx.x;
  if (e < NE) atomicAdd(&g_deg[tgt[e]], 1);
}

// ---------------- exclusive scan over deg -> row_ptr (single block)
__global__ void k_scan(){
  __shared__ int sh[1024];
  int tid = threadIdx.x;
  const int CH = (NN + 1023) / 1024;  // 49
  int st = tid * CH, en = st + CH;
  if (en > NN) en = NN;
  int s = 0;
  if (st < NN) for (int i = st; i < en; i++) s += g_deg[i];
  sh[tid] = s;
  __syncthreads();
  for (int off = 1; off < 1024; off <<= 1){
    int v = (tid >= off) ? sh[tid - off] : 0;
    __syncthreads();
    sh[tid] += v;
    __syncthreads();
  }
  int run = (tid == 0) ? 0 : sh[tid - 1];
  if (st < NN){
    for (int i = st; i < en; i++){ g_rowptr[i] = run; run += g_deg[i]; }
    if (en == NN) g_rowptr[NN] = run;
  }
}

// ---------------- CSR fill
__global__ void k_fill(const int* __restrict__ src, const int* __restrict__ tgt){
  int e = blockIdx.x * 256 + threadIdx.x;
  if (e >= NE) return;
  int t = tgt[e];
  int pos = g_rowptr[t] + atomicAdd(&g_cursor[t], 1);
  g_colidx[pos] = src[e];
}

// ---------------- dinv = (indeg+1)^-0.5
__global__ void k_dinv(){
  int i = blockIdx.x * 256 + threadIdx.x;
  if (i < NN) g_dinv[i] = 1.0f / sqrtf((float)(g_deg[i] + 1));
}

// ---------------- unweighted neighbor sum: bufA[t] = sum_{e: tgt=t} bufB[src_e]
__global__ __launch_bounds__(256) void k_aggsum(){
  int g = threadIdx.x >> 5, lane = threadIdx.x & 31;
  int node = blockIdx.x * 8 + g;
  if (node >= NN) return;
  const int c4 = lane * 4;
  float a0 = 0.f, a1 = 0.f, a2 = 0.f, a3 = 0.f;
  int p0 = g_rowptr[node], p1 = g_rowptr[node + 1];
  for (int p = p0; p < p1; p++){
    int s = g_colidx[p];
    ushort4 v = *reinterpret_cast<const ushort4*>(&g_bufB[(size_t)s * 128 + c4]);
    a0 += b2f(v.x); a1 += b2f(v.y); a2 += b2f(v.z); a3 += b2f(v.w);
  }
  ushort4 o; o.x = f2b(a0); o.y = f2b(a1); o.z = f2b(a2); o.w = f2b(a3);
  *reinterpret_cast<ushort4*>(&g_bufA[(size_t)node * 128 + c4]) = o;
}

// ---------------- GCN normalized aggregate into bufA; SEL: 0 from bufC, 1 from bufB
template<int SEL>
__global__ __launch_bounds__(256) void k_aggnorm(){
  const unsigned short* x = (SEL == 0) ? g_bufC : g_bufB;
  int g = threadIdx.x >> 5, lane = threadIdx.x & 31;
  int node = blockIdx.x * 8 + g;
  if (node >= NN) return;
  const int c4 = lane * 4;
  float wt = g_dinv[node];
  float wself = wt * wt;
  ushort4 sv = *reinterpret_cast<const ushort4*>(&x[(size_t)node * 128 + c4]);
  float a0 = wself * b2f(sv.x), a1 = wself * b2f(sv.y);
  float a2 = wself * b2f(sv.z), a3 = wself * b2f(sv.w);
  int p0 = g_rowptr[node], p1 = g_rowptr[node + 1];
  for (int p = p0; p < p1; p++){
    int s = g_colidx[p];
    float w = g_dinv[s] * wt;
    ushort4 v = *reinterpret_cast<const ushort4*>(&x[(size_t)s * 128 + c4]);
    a0 += w * b2f(v.x); a1 += w * b2f(v.y); a2 += w * b2f(v.z); a3 += w * b2f(v.w);
  }
  ushort4 o; o.x = f2b(a0); o.y = f2b(a1); o.z = f2b(a2); o.w = f2b(a3);
  *reinterpret_cast<ushort4*>(&g_bufA[(size_t)node * 128 + c4]) = o;
}

// ---------------- GEMM + bias + LayerNorm + ReLU
// SEL 0: A=g_X [N,512], Bt=g_W1t[112][512], out=g_bufA
// SEL 1: A=g_bufA [N,128], Bt=g_W2t[112][128], out=g_bufB
template<int SEL>
__global__ __launch_bounds__(256) void k_gemm_ln(const void* __restrict__ bias,
    const void* __restrict__ gamma, const void* __restrict__ beta){
  constexpr int KPAD = (SEL == 0) ? 512 : 128;
  const unsigned short* Bt = (SEL == 0) ? g_W1t : g_W2t;
  const unsigned short* A  = (SEL == 0) ? g_X : g_bufA;
  unsigned short* out      = (SEL == 0) ? g_bufA : g_bufB;
  const int isf32 = g_isf32;

  const int wave = threadIdx.x >> 6, lane = threadIdx.x & 63;
  const int m = lane & 15, q = lane >> 4;
  const int row0 = (blockIdx.x * 4 + wave) * 16;
  if (row0 >= NN) return;
  const unsigned short* arow = A + (size_t)(row0 + m) * KPAD;
  f32x4 acc[7] = {};
  constexpr int CHN = KPAD / 32;
#pragma unroll
  for (int c = 0; c < CHN; c++){
    const int k0 = c * 32 + q * 8;
    short8 a = *reinterpret_cast<const short8*>(arow + k0);
#pragma unroll
    for (int t = 0; t < 7; t++){
      short8 b = *reinterpret_cast<const short8*>(Bt + (size_t)(t * 16 + m) * KPAD + k0);
      acc[t] = MFMA16x16x32(a, b, acc[t], 0, 0, 0);
    }
  }
  float bf_[7], gf_[7], ef_[7];
#pragma unroll
  for (int t = 0; t < 7; t++){
    int col = t * 16 + m;
    bool ok = col < 100;
    bf_[t] = ok ? ld_in(bias, col, isf32)  : 0.f;
    gf_[t] = ok ? ld_in(gamma, col, isf32) : 0.f;
    ef_[t] = ok ? ld_in(beta, col, isf32)  : 0.f;
  }
#pragma unroll
  for (int r = 0; r < 4; r++){
    float vals[7], s1 = 0.f, s2 = 0.f;
#pragma unroll
    for (int t = 0; t < 7; t++){
      int col = t * 16 + m;
      float v = (col < 100) ? (acc[t][r] + bf_[t]) : 0.f;
      vals[t] = v; s1 += v; s2 += v * v;
    }
#pragma unroll
    for (int msk = 1; msk < 16; msk <<= 1){
      s1 += __shfl_xor(s1, msk, 64);
      s2 += __shfl_xor(s2, msk, 64);
    }
    float mu = s1 * 0.01f;
    float var = fmaxf(s2 * 0.01f - mu * mu, 0.f);
    float rstd = rsqrtf(var + 1e-5f);
    unsigned short* orow = out + (size_t)(row0 + q * 4 + r) * 128;
#pragma unroll
    for (int t = 0; t < 7; t++){
      int col = t * 16 + m;
      float y = fmaxf((vals[t] - mu) * rstd * gf_[t] + ef_[t], 0.f);
      orow[col] = f2b((col < 100) ? y : 0.f);
    }
    orow[112 + m] = 0;
  }
}

// ---------------- (A1@B1t [+ A2@B2t]) + bias, ReLU. K=128.
// SEL 0 (dual, RGCN): bufB@WselfT + bufA@WrelT -> bufC
// SEL 1 (single, GCN1): bufA@c1Wt -> bufB
template<int SEL>
__global__ __launch_bounds__(256) void k_gemm_bias_relu(const void* __restrict__ bias){
  const unsigned short* A1  = (SEL == 0) ? g_bufB : g_bufA;
  const unsigned short* B1t = (SEL == 0) ? g_WselfT : g_c1Wt;
  unsigned short* out       = (SEL == 0) ? g_bufC : g_bufB;
  const int isf32 = g_isf32;

  const int wave = threadIdx.x >> 6, lane = threadIdx.x & 63;
  const int m = lane & 15, q = lane >> 4;
  const int row0 = (blockIdx.x * 4 + wave) * 16;
  if (row0 >= NN) return;
  f32x4 acc[7] = {};
  const unsigned short* a1row = A1 + (size_t)(row0 + m) * 128;
#pragma unroll
  for (int c = 0; c < 4; c++){
    const int k0 = c * 32 + q * 8;
    short8 a = *reinterpret_cast<const short8*>(a1row + k0);
#pragma unroll
    for (int t = 0; t < 7; t++){
      short8 b = *reinterpret_cast<const short8*>(B1t + (size_t)(t * 16 + m) * 128 + k0);
      acc[t] = MFMA16x16x32(a, b, acc[t], 0, 0, 0);
    }
  }
  if (SEL == 0){
    const unsigned short* a2row = g_bufA + (size_t)(row0 + m) * 128;
#pragma unroll
    for (int c = 0; c < 4; c++){
      const int k0 = c * 32 + q * 8;
      short8 a = *reinterpret_cast<const short8*>(a2row + k0);
#pragma unroll
      for (int t = 0; t < 7; t++){
        short8 b = *reinterpret_cast<const short8*>(g_WrelT + (size_t)(t * 16 + m) * 128 + k0);
        acc[t] = MFMA16x16x32(a, b, acc[t], 0, 0, 0);
      }
    }
  }
  float bf_[7];
#pragma unroll
  for (int t = 0; t < 7; t++){
    int col = t * 16 + m;
    bf_[t] = (col < 100) ? ld_in(bias, col, isf32) : 0.f;
  }
#pragma unroll
  for (int r = 0; r < 4; r++){
    unsigned short* orow = out + (size_t)(row0 + q * 4 + r) * 128;
#pragma unroll
    for (int t = 0; t < 7; t++){
      int col = t * 16 + m;
      float y = fmaxf(acc[t][r] + bf_[t], 0.f);
      orow[col] = f2b((col < 100) ? y : 0.f);
    }
    orow[112 + m] = 0;
  }
}

// ---------------- bufA@c2Wt + bias -> log_softmax over 64 cols -> d_out [N,64]
__global__ __launch_bounds__(256) void k_gemm_lsm(const void* __restrict__ bias,
                                                  void* __restrict__ outv){
  const int isf32 = g_isf32;
  const int wave = threadIdx.x >> 6, lane = threadIdx.x & 63;
  const int m = lane & 15, q = lane >> 4;
  const int row0 = (blockIdx.x * 4 + wave) * 16;
  if (row0 >= NN) return;
  f32x4 acc[4] = {};
  const unsigned short* arow = g_bufA + (size_t)(row0 + m) * 128;
#pragma unroll
  for (int c = 0; c < 4; c++){
    const int k0 = c * 32 + q * 8;
    short8 a = *reinterpret_cast<const short8*>(arow + k0);
#pragma unroll
    for (int t = 0; t < 4; t++){
      short8 b = *reinterpret_cast<const short8*>(g_c2Wt + (size_t)(t * 16 + m) * 128 + k0);
      acc[t] = MFMA16x16x32(a, b, acc[t], 0, 0, 0);
    }
  }
  float bf_[4];
#pragma unroll
  for (int t = 0; t < 4; t++) bf_[t] = ld_in(bias, t * 16 + m, isf32);
#pragma unroll
  for (int r = 0; r < 4; r++){
    float vals[4], mx = -1e30f;
#pragma unroll
    for (int t = 0; t < 4; t++){
      float v = acc[t][r] + bf_[t];
      vals[t] = v; mx = fmaxf(mx, v);
    }
#pragma unroll
    for (int msk = 1; msk < 16; msk <<= 1) mx = fmaxf(mx, __shfl_xor(mx, msk, 64));
    float se = 0.f;
#pragma unroll
    for (int t = 0; t < 4; t++) se += expf(vals[t] - mx);
#pragma unroll
    for (int msk = 1; msk < 16; msk <<= 1) se += __shfl_xor(se, msk, 64);
    float lse = logf(se);
    size_t ro = (size_t)(row0 + q * 4 + r) * 64;
    if (isf32){
      float* orow = (float*)outv + ro;
#pragma unroll
      for (int t = 0; t < 4; t++) orow[t * 16 + m] = vals[t] - mx - lse;
    } else {
      unsigned short* orow = (unsigned short*)outv + ro;
#pragma unroll
      for (int t = 0; t < 4; t++) orow[t * 16 + m] = f2b(vals[t] - mx - lse);
    }
  }
}

extern "C" void kernel_launch(void* const* d_in, const int* in_sizes, int n_in,
                              void* d_out, int out_size, void* d_ws, size_t ws_size,
                              hipStream_t stream){
  (void)in_sizes; (void)n_in; (void)out_size; (void)d_ws; (void)ws_size;
  const void* data_x = d_in[0];
  const int* ei = (const int*)d_in[1];
  const int* src = ei;
  const int* tgt = ei + NE;
  const void *W1 = d_in[3], *b1 = d_in[4], *gm1 = d_in[5], *be1 = d_in[6];
  const void *W2 = d_in[7], *b2 = d_in[8], *gm2 = d_in[9], *be2 = d_in[10];
  const void *Wrel = d_in[11], *Wself = d_in[12], *rb = d_in[13];
  const void *c1W = d_in[14], *c1b = d_in[15];
  const void *c2W = d_in[16], *c2b = d_in[17];

  k_detect<<<1, 256, 0, stream>>>((const unsigned short*)data_x);
  k_zero<<<(NN + 255) / 256, 256, 0, stream>>>();
  k_stagex<<<(NN * 512 + 255) / 256, 256, 0, stream>>>(data_x);
  k_transpose<0><<<(112 * 512 + 255) / 256, 256, 0, stream>>>(W1);
  k_transpose<1><<<(112 * 128 + 255) / 256, 256, 0, stream>>>(W2);
  k_transpose<2><<<(112 * 128 + 255) / 256, 256, 0, stream>>>(Wself);
  k_transpose<3><<<(112 * 128 + 255) / 256, 256, 0, stream>>>(Wrel);
  k_transpose<4><<<(112 * 128 + 255) / 256, 256, 0, stream>>>(c1W);
  k_transpose<5><<<(64 * 128 + 255) / 256, 256, 0, stream>>>(c2W);

  k_deg<<<(NE + 255) / 256, 256, 0, stream>>>(tgt);
  k_scan<<<1, 1024, 0, stream>>>();
  k_fill<<<(NE + 255) / 256, 256, 0, stream>>>(src, tgt);
  k_dinv<<<(NN + 255) / 256, 256, 0, stream>>>();

  const int GB = (NN / 16 + 3) / 4;  // 782 blocks, 4 waves x 16 rows
  // transform: Linear->LN->ReLU twice
  k_gemm_ln<0><<<GB, 256, 0, stream>>>(b1, gm1, be1);   // g_X -> bufA
  k_gemm_ln<1><<<GB, 256, 0, stream>>>(b2, gm2, be2);   // bufA -> bufB
  // RGCN (aggregate-then-matmul; segment_sum commutes with shared W)
  k_aggsum<<<(NN + 7) / 8, 256, 0, stream>>>();         // bufB -> bufA
  k_gemm_bias_relu<0><<<GB, 256, 0, stream>>>(rb);      // bufB@Wself + bufA@Wrel -> bufC
  // GCNConv1
  k_aggnorm<0><<<(NN + 7) / 8, 256, 0, stream>>>();     // bufC -> bufA
  k_gemm_bias_relu<1><<<GB, 256, 0, stream>>>(c1b);     // bufA@c1W -> bufB
  // GCNConv2 + log_softmax
  k_aggnorm<1><<<(NN + 7) / 8, 256, 0, stream>>>();     // bufB -> bufA
  k_gemm_lsm<<<GB, 256, 0, stream>>>(c2b, d_out);
}

// Round 4
// 635.298 us; speedup vs baseline: 1.1274x; 1.1274x over previous
//
#include <hip/hip_runtime.h>
#include <hip/hip_bf16.h>

typedef __attribute__((ext_vector_type(8))) short short8;
typedef __attribute__((ext_vector_type(4))) float f32x4;

static constexpr int NN = 50000;   // nodes
static constexpr int NE = 800000;  // edges
static constexpr int SCAN_B = 196; // ceil(NN/256)

#define MFMA16x16x32 __builtin_amdgcn_mfma_f32_16x16x32_bf16

__device__ __forceinline__ float b2f(unsigned short u){
  unsigned v = ((unsigned)u) << 16;
  return __builtin_bit_cast(float, v);
}
__device__ __forceinline__ unsigned short f2b(float f){
  unsigned x = __builtin_bit_cast(unsigned, f);
  unsigned r = (x + 0x7fffu + ((x >> 16) & 1u)) >> 16;  // RNE
  return (unsigned short)r;
}

// ---------------- static device scratch (module-load allocated; d_ws unused)
__device__ __align__(256) int   g_isf32;                     // runtime dtype flag
__device__ __align__(256) unsigned short g_X   [(size_t)NN * 512];  // staged data_x, bf16, K 500->512
__device__ __align__(256) unsigned short g_W1t  [112 * 512];
__device__ __align__(256) unsigned short g_W2t  [112 * 128];
__device__ __align__(256) unsigned short g_WselfT[112 * 128];
__device__ __align__(256) unsigned short g_WrelT [112 * 128];
__device__ __align__(256) unsigned short g_c1Wt [112 * 128];
__device__ __align__(256) unsigned short g_c2Wt [64 * 128];
__device__ __align__(256) unsigned short g_bufA[(size_t)NN * 128];
__device__ __align__(256) unsigned short g_bufB[(size_t)NN * 128];
__device__ __align__(256) unsigned short g_bufC[(size_t)NN * 128];
__device__ __align__(256) int   g_deg[NN];
__device__ __align__(256) int   g_rowptr[NN + 1];
__device__ __align__(256) int   g_cursor[NN];
__device__ __align__(256) int   g_colidx[NE];
__device__ __align__(256) float g_dinv[NN];
__device__ __align__(256) int   g_partial[256];   // block totals for 2-level scan

__device__ __forceinline__ float ld_in(const void* p, int idx, int isf32){
  if (isf32) return ((const float*)p)[idx];
  return b2f(((const unsigned short*)p)[idx]);
}

// ---------------- dtype sniffer: even halfwords of f32 data are uniform mantissa
__global__ void k_detect(const unsigned short* __restrict__ x){
  __shared__ int sh[256];
  int tid = threadIdx.x;
  int cnt = 0;
  for (int j = 0; j < 16; j++){
    unsigned short h = x[(size_t)(tid * 16 + j) * 2];
    int e = (h >> 7) & 0xFF;
    if (e >= 90 && e <= 160) cnt++;
  }
  sh[tid] = cnt;
  __syncthreads();
  for (int off = 128; off > 0; off >>= 1){
    if (tid < off) sh[tid] += sh[tid + off];
    __syncthreads();
  }
  if (tid == 0) g_isf32 = (sh[0] < 2458) ? 1 : 0;
}

// ---------------- zero deg/cursor each call
__global__ void k_zero(){
  int i = blockIdx.x * 256 + threadIdx.x;
  if (i < NN){ g_deg[i] = 0; g_cursor[i] = 0; }
}

// ---------------- stage data_x -> g_X [NN][512] bf16, zero-padded
__global__ void k_stagex(const void* __restrict__ x){
  int idx = blockIdx.x * 256 + threadIdx.x;
  if (idx >= NN * 512) return;
  int n = idx >> 9, k = idx & 511;
  unsigned short v = 0;
  if (k < 500){
    if (g_isf32) v = f2b(((const float*)x)[(size_t)n * 500 + k]);
    else         v = ((const unsigned short*)x)[(size_t)n * 500 + k];
  }
  g_X[idx] = v;
}

// ---------------- all 6 weight transposes in ONE launch (range-decoded)
// seg layout: [0,57344) W1; +14336 each: W2, Wself, Wrel, c1W; [114688,122880) c2W
__device__ __forceinline__ void xp_one(const void* W, unsigned short* Wt, int idx,
                                       int K, int Nc, int Kpad, int isf32){
  int n = idx / Kpad;
  int k = idx - n * Kpad;
  float v = 0.f;
  if (n < Nc && k < K) v = ld_in(W, k * Nc + n, isf32);
  Wt[idx] = f2b(v);
}
__global__ void k_transpose_all(const void* W1, const void* W2, const void* Wself,
                                const void* Wrel, const void* c1W, const void* c2W){
  int idx = blockIdx.x * 256 + threadIdx.x;
  const int isf32 = g_isf32;
  if (idx < 57344){ xp_one(W1, g_W1t, idx, 500, 100, 512, isf32); return; }
  idx -= 57344;
  if (idx < 14336){ xp_one(W2,    g_W2t,    idx, 100, 100, 128, isf32); return; }
  idx -= 14336;
  if (idx < 14336){ xp_one(Wself, g_WselfT, idx, 100, 100, 128, isf32); return; }
  idx -= 14336;
  if (idx < 14336){ xp_one(Wrel,  g_WrelT,  idx, 100, 100, 128, isf32); return; }
  idx -= 14336;
  if (idx < 14336){ xp_one(c1W,   g_c1Wt,   idx, 100, 100, 128, isf32); return; }
  idx -= 14336;
  if (idx < 8192){  xp_one(c2W,   g_c2Wt,   idx, 100, 64,  128, isf32); }
}

// ---------------- degree histogram (in-degree by tgt)
__global__ void k_deg(const int* __restrict__ tgt){
  int e = blockIdx.x * 256 + threadIdx.x;
  if (e < NE) atomicAdd(&g_deg[tgt[e]], 1);
}

// ---------------- two-level scan. scan1: per-block exclusive prefix + block total
// (fuses dinv = (deg+1)^-0.5 — reads deg anyway)
__global__ __launch_bounds__(256) void k_scan1(){
  __shared__ int sh[256];
  int t = threadIdx.x;
  int i = blockIdx.x * 256 + t;
  int val = (i < NN) ? g_deg[i] : 0;
  sh[t] = val;
  __syncthreads();
#pragma unroll
  for (int off = 1; off < 256; off <<= 1){
    int v = (t >= off) ? sh[t - off] : 0;
    __syncthreads();
    sh[t] += v;
    __syncthreads();
  }
  if (i < NN){
    g_rowptr[i] = sh[t] - val;           // block-local exclusive
    g_dinv[i] = rsqrtf((float)(val + 1));
  }
  if (t == 255) g_partial[blockIdx.x] = sh[255];
}
// scan2: one block scans the 196 block totals -> exclusive; writes rowptr[NN]=total
__global__ __launch_bounds__(256) void k_scan2(){
  __shared__ int sh[256];
  int t = threadIdx.x;
  int val = (t < SCAN_B) ? g_partial[t] : 0;
  sh[t] = val;
  __syncthreads();
#pragma unroll
  for (int off = 1; off < 256; off <<= 1){
    int v = (t >= off) ? sh[t - off] : 0;
    __syncthreads();
    sh[t] += v;
    __syncthreads();
  }
  if (t < SCAN_B) g_partial[t] = sh[t] - val;  // exclusive block offsets
  if (t == 255) g_rowptr[NN] = sh[255];
}
// scan3: add block offsets
__global__ __launch_bounds__(256) void k_scan3(){
  int i = blockIdx.x * 256 + threadIdx.x;
  if (i < NN) g_rowptr[i] += g_partial[blockIdx.x];
}

// ---------------- CSR fill
__global__ void k_fill(const int* __restrict__ src, const int* __restrict__ tgt){
  int e = blockIdx.x * 256 + threadIdx.x;
  if (e >= NE) return;
  int t = tgt[e];
  int pos = g_rowptr[t] + atomicAdd(&g_cursor[t], 1);
  g_colidx[pos] = src[e];
}

// ---------------- unweighted neighbor sum: bufA[t] = sum_{e: tgt=t} bufB[src_e]
__global__ __launch_bounds__(256) void k_aggsum(){
  int g = threadIdx.x >> 5, lane = threadIdx.x & 31;
  int node = blockIdx.x * 8 + g;
  if (node >= NN) return;
  const int c4 = lane * 4;
  float a0 = 0.f, a1 = 0.f, a2 = 0.f, a3 = 0.f;
  int p0 = g_rowptr[node], p1 = g_rowptr[node + 1];
  for (int p = p0; p < p1; p++){
    int s = g_colidx[p];
    ushort4 v = *reinterpret_cast<const ushort4*>(&g_bufB[(size_t)s * 128 + c4]);
    a0 += b2f(v.x); a1 += b2f(v.y); a2 += b2f(v.z); a3 += b2f(v.w);
  }
  ushort4 o; o.x = f2b(a0); o.y = f2b(a1); o.z = f2b(a2); o.w = f2b(a3);
  *reinterpret_cast<ushort4*>(&g_bufA[(size_t)node * 128 + c4]) = o;
}

// ---------------- GCN normalized aggregate into bufA; SEL: 0 from bufC, 1 from bufB
template<int SEL>
__global__ __launch_bounds__(256) void k_aggnorm(){
  const unsigned short* x = (SEL == 0) ? g_bufC : g_bufB;
  int g = threadIdx.x >> 5, lane = threadIdx.x & 31;
  int node = blockIdx.x * 8 + g;
  if (node >= NN) return;
  const int c4 = lane * 4;
  float wt = g_dinv[node];
  float wself = wt * wt;
  ushort4 sv = *reinterpret_cast<const ushort4*>(&x[(size_t)node * 128 + c4]);
  float a0 = wself * b2f(sv.x), a1 = wself * b2f(sv.y);
  float a2 = wself * b2f(sv.z), a3 = wself * b2f(sv.w);
  int p0 = g_rowptr[node], p1 = g_rowptr[node + 1];
  for (int p = p0; p < p1; p++){
    int s = g_colidx[p];
    float w = g_dinv[s] * wt;
    ushort4 v = *reinterpret_cast<const ushort4*>(&x[(size_t)s * 128 + c4]);
    a0 += w * b2f(v.x); a1 += w * b2f(v.y); a2 += w * b2f(v.z); a3 += w * b2f(v.w);
  }
  ushort4 o; o.x = f2b(a0); o.y = f2b(a1); o.z = f2b(a2); o.w = f2b(a3);
  *reinterpret_cast<ushort4*>(&g_bufA[(size_t)node * 128 + c4]) = o;
}

// ---------------- GEMM + bias + LayerNorm + ReLU
template<int SEL>
__global__ __launch_bounds__(256) void k_gemm_ln(const void* __restrict__ bias,
    const void* __restrict__ gamma, const void* __restrict__ beta){
  constexpr int KPAD = (SEL == 0) ? 512 : 128;
  const unsigned short* Bt = (SEL == 0) ? g_W1t : g_W2t;
  const unsigned short* A  = (SEL == 0) ? g_X : g_bufA;
  unsigned short* out      = (SEL == 0) ? g_bufA : g_bufB;
  const int isf32 = g_isf32;

  const int wave = threadIdx.x >> 6, lane = threadIdx.x & 63;
  const int m = lane & 15, q = lane >> 4;
  const int row0 = (blockIdx.x * 4 + wave) * 16;
  if (row0 >= NN) return;
  const unsigned short* arow = A + (size_t)(row0 + m) * KPAD;
  f32x4 acc[7] = {};
  constexpr int CHN = KPAD / 32;
#pragma unroll
  for (int c = 0; c < CHN; c++){
    const int k0 = c * 32 + q * 8;
    short8 a = *reinterpret_cast<const short8*>(arow + k0);
#pragma unroll
    for (int t = 0; t < 7; t++){
      short8 b = *reinterpret_cast<const short8*>(Bt + (size_t)(t * 16 + m) * KPAD + k0);
      acc[t] = MFMA16x16x32(a, b, acc[t], 0, 0, 0);
    }
  }
  float bf_[7], gf_[7], ef_[7];
#pragma unroll
  for (int t = 0; t < 7; t++){
    int col = t * 16 + m;
    bool ok = col < 100;
    bf_[t] = ok ? ld_in(bias, col, isf32)  : 0.f;
    gf_[t] = ok ? ld_in(gamma, col, isf32) : 0.f;
    ef_[t] = ok ? ld_in(beta, col, isf32)  : 0.f;
  }
#pragma unroll
  for (int r = 0; r < 4; r++){
    float vals[7], s1 = 0.f, s2 = 0.f;
#pragma unroll
    for (int t = 0; t < 7; t++){
      int col = t * 16 + m;
      float v = (col < 100) ? (acc[t][r] + bf_[t]) : 0.f;
      vals[t] = v; s1 += v; s2 += v * v;
    }
#pragma unroll
    for (int msk = 1; msk < 16; msk <<= 1){
      s1 += __shfl_xor(s1, msk, 64);
      s2 += __shfl_xor(s2, msk, 64);
    }
    float mu = s1 * 0.01f;
    float var = fmaxf(s2 * 0.01f - mu * mu, 0.f);
    float rstd = rsqrtf(var + 1e-5f);
    unsigned short* orow = out + (size_t)(row0 + q * 4 + r) * 128;
#pragma unroll
    for (int t = 0; t < 7; t++){
      int col = t * 16 + m;
      float y = fmaxf((vals[t] - mu) * rstd * gf_[t] + ef_[t], 0.f);
      orow[col] = f2b((col < 100) ? y : 0.f);
    }
    orow[112 + m] = 0;
  }
}

// ---------------- (A1@B1t [+ A2@B2t]) + bias, ReLU. K=128.
template<int SEL>
__global__ __launch_bounds__(256) void k_gemm_bias_relu(const void* __restrict__ bias){
  const unsigned short* A1  = (SEL == 0) ? g_bufB : g_bufA;
  const unsigned short* B1t = (SEL == 0) ? g_WselfT : g_c1Wt;
  unsigned short* out       = (SEL == 0) ? g_bufC : g_bufB;
  const int isf32 = g_isf32;

  const int wave = threadIdx.x >> 6, lane = threadIdx.x & 63;
  const int m = lane & 15, q = lane >> 4;
  const int row0 = (blockIdx.x * 4 + wave) * 16;
  if (row0 >= NN) return;
  f32x4 acc[7] = {};
  const unsigned short* a1row = A1 + (size_t)(row0 + m) * 128;
#pragma unroll
  for (int c = 0; c < 4; c++){
    const int k0 = c * 32 + q * 8;
    short8 a = *reinterpret_cast<const short8*>(a1row + k0);
#pragma unroll
    for (int t = 0; t < 7; t++){
      short8 b = *reinterpret_cast<const short8*>(B1t + (size_t)(t * 16 + m) * 128 + k0);
      acc[t] = MFMA16x16x32(a, b, acc[t], 0, 0, 0);
    }
  }
  if (SEL == 0){
    const unsigned short* a2row = g_bufA + (size_t)(row0 + m) * 128;
#pragma unroll
    for (int c = 0; c < 4; c++){
      const int k0 = c * 32 + q * 8;
      short8 a = *reinterpret_cast<const short8*>(a2row + k0);
#pragma unroll
      for (int t = 0; t < 7; t++){
        short8 b = *reinterpret_cast<const short8*>(g_WrelT + (size_t)(t * 16 + m) * 128 + k0);
        acc[t] = MFMA16x16x32(a, b, acc[t], 0, 0, 0);
      }
    }
  }
  float bf_[7];
#pragma unroll
  for (int t = 0; t < 7; t++){
    int col = t * 16 + m;
    bf_[t] = (col < 100) ? ld_in(bias, col, isf32) : 0.f;
  }
#pragma unroll
  for (int r = 0; r < 4; r++){
    unsigned short* orow = out + (size_t)(row0 + q * 4 + r) * 128;
#pragma unroll
    for (int t = 0; t < 7; t++){
      int col = t * 16 + m;
      float y = fmaxf(acc[t][r] + bf_[t], 0.f);
      orow[col] = f2b((col < 100) ? y : 0.f);
    }
    orow[112 + m] = 0;
  }
}

// ---------------- bufA@c2Wt + bias -> log_softmax over 64 cols -> d_out [N,64]
__global__ __launch_bounds__(256) void k_gemm_lsm(const void* __restrict__ bias,
                                                  void* __restrict__ outv){
  const int isf32 = g_isf32;
  const int wave = threadIdx.x >> 6, lane = threadIdx.x & 63;
  const int m = lane & 15, q = lane >> 4;
  const int row0 = (blockIdx.x * 4 + wave) * 16;
  if (row0 >= NN) return;
  f32x4 acc[4] = {};
  const unsigned short* arow = g_bufA + (size_t)(row0 + m) * 128;
#pragma unroll
  for (int c = 0; c < 4; c++){
    const int k0 = c * 32 + q * 8;
    short8 a = *reinterpret_cast<const short8*>(arow + k0);
#pragma unroll
    for (int t = 0; t < 4; t++){
      short8 b = *reinterpret_cast<const short8*>(g_c2Wt + (size_t)(t * 16 + m) * 128 + k0);
      acc[t] = MFMA16x16x32(a, b, acc[t], 0, 0, 0);
    }
  }
  float bf_[4];
#pragma unroll
  for (int t = 0; t < 4; t++) bf_[t] = ld_in(bias, t * 16 + m, isf32);
#pragma unroll
  for (int r = 0; r < 4; r++){
    float vals[4], mx = -1e30f;
#pragma unroll
    for (int t = 0; t < 4; t++){
      float v = acc[t][r] + bf_[t];
      vals[t] = v; mx = fmaxf(mx, v);
    }
#pragma unroll
    for (int msk = 1; msk < 16; msk <<= 1) mx = fmaxf(mx, __shfl_xor(mx, msk, 64));
    float se = 0.f;
#pragma unroll
    for (int t = 0; t < 4; t++) se += expf(vals[t] - mx);
#pragma unroll
    for (int msk = 1; msk < 16; msk <<= 1) se += __shfl_xor(se, msk, 64);
    float lse = logf(se);
    size_t ro = (size_t)(row0 + q * 4 + r) * 64;
    if (isf32){
      float* orow = (float*)outv + ro;
#pragma unroll
      for (int t = 0; t < 4; t++) orow[t * 16 + m] = vals[t] - mx - lse;
    } else {
      unsigned short* orow = (unsigned short*)outv + ro;
#pragma unroll
      for (int t = 0; t < 4; t++) orow[t * 16 + m] = f2b(vals[t] - mx - lse);
    }
  }
}

extern "C" void kernel_launch(void* const* d_in, const int* in_sizes, int n_in,
                              void* d_out, int out_size, void* d_ws, size_t ws_size,
                              hipStream_t stream){
  (void)in_sizes; (void)n_in; (void)out_size; (void)d_ws; (void)ws_size;
  const void* data_x = d_in[0];
  const int* ei = (const int*)d_in[1];
  const int* src = ei;
  const int* tgt = ei + NE;
  const void *W1 = d_in[3], *b1 = d_in[4], *gm1 = d_in[5], *be1 = d_in[6];
  const void *b2 = d_in[8], *gm2 = d_in[9], *be2 = d_in[10];
  const void *W2 = d_in[7];
  const void *Wrel = d_in[11], *Wself = d_in[12], *rb = d_in[13];
  const void *c1W = d_in[14], *c1b = d_in[15];
  const void *c2W = d_in[16], *c2b = d_in[17];

  k_detect<<<1, 256, 0, stream>>>((const unsigned short*)data_x);
  k_zero<<<(NN + 255) / 256, 256, 0, stream>>>();
  k_stagex<<<(NN * 512 + 255) / 256, 256, 0, stream>>>(data_x);
  k_transpose_all<<<(122880 + 255) / 256, 256, 0, stream>>>(W1, W2, Wself, Wrel, c1W, c2W);

  k_deg<<<(NE + 255) / 256, 256, 0, stream>>>(tgt);
  k_scan1<<<SCAN_B, 256, 0, stream>>>();
  k_scan2<<<1, 256, 0, stream>>>();
  k_scan3<<<SCAN_B, 256, 0, stream>>>();
  k_fill<<<(NE + 255) / 256, 256, 0, stream>>>(src, tgt);

  const int GB = (NN / 16 + 3) / 4;  // 782 blocks, 4 waves x 16 rows
  k_gemm_ln<0><<<GB, 256, 0, stream>>>(b1, gm1, be1);   // g_X -> bufA
  k_gemm_ln<1><<<GB, 256, 0, stream>>>(b2, gm2, be2);   // bufA -> bufB
  k_aggsum<<<(NN + 7) / 8, 256, 0, stream>>>();         // bufB -> bufA
  k_gemm_bias_relu<0><<<GB, 256, 0, stream>>>(rb);      // bufB@Wself + bufA@Wrel -> bufC
  k_aggnorm<0><<<(NN + 7) / 8, 256, 0, stream>>>();     // bufC -> bufA
  k_gemm_bias_relu<1><<<GB, 256, 0, stream>>>(c1b);     // bufA@c1W -> bufB
  k_aggnorm<1><<<(NN + 7) / 8, 256, 0, stream>>>();     // bufB -> bufA
  k_gemm_lsm<<<GB, 256, 0, stream>>>(c2b, d_out);
}

// Round 5
// 526.356 us; speedup vs baseline: 1.3608x; 1.2070x over previous
//
#include <hip/hip_runtime.h>
#include <hip/hip_bf16.h>

typedef __attribute__((ext_vector_type(8))) short short8;
typedef __attribute__((ext_vector_type(8))) unsigned short ushort8;
typedef __attribute__((ext_vector_type(4))) float f32x4;

static constexpr int NN = 50000;   // nodes
static constexpr int NE = 800000;  // edges
static constexpr int SCAN_B = 196; // ceil(NN/256)

#define MFMA16x16x32 __builtin_amdgcn_mfma_f32_16x16x32_bf16

__device__ __forceinline__ float b2f(unsigned short u){
  unsigned v = ((unsigned)u) << 16;
  return __builtin_bit_cast(float, v);
}
__device__ __forceinline__ unsigned short f2b(float f){
  unsigned x = __builtin_bit_cast(unsigned, f);
  unsigned r = (x + 0x7fffu + ((x >> 16) & 1u)) >> 16;  // RNE
  return (unsigned short)r;
}

// ---------------- static device scratch (module-load allocated; d_ws unused)
__device__ __align__(256) int   g_isf32;
__device__ __align__(256) unsigned short g_W1t  [112 * 512];
__device__ __align__(256) unsigned short g_W2t  [112 * 128];
__device__ __align__(256) unsigned short g_WselfT[112 * 128];
__device__ __align__(256) unsigned short g_WrelT [112 * 128];
__device__ __align__(256) unsigned short g_c1Wt [112 * 128];
__device__ __align__(256) unsigned short g_c2Wt [64 * 128];
__device__ __align__(256) unsigned short g_bufA[(size_t)NN * 128];
__device__ __align__(256) unsigned short g_bufB[(size_t)NN * 128];
__device__ __align__(256) unsigned short g_bufC[(size_t)NN * 128];
__device__ __align__(256) int   g_deg[NN];
__device__ __align__(256) int   g_rowptr[NN + 1];
__device__ __align__(256) int   g_cursor[NN];
__device__ __align__(256) int   g_colidx[NE];
__device__ __align__(256) float g_dinv[NN];
__device__ __align__(256) int   g_partial[256];

__device__ __forceinline__ float ld_in(const void* p, int idx, int isf32){
  if (isf32) return ((const float*)p)[idx];
  return b2f(((const unsigned short*)p)[idx]);
}

// ---------------- dtype sniffer
__global__ void k_detect(const unsigned short* __restrict__ x){
  __shared__ int sh[256];
  int tid = threadIdx.x;
  int cnt = 0;
  for (int j = 0; j < 16; j++){
    unsigned short h = x[(size_t)(tid * 16 + j) * 2];
    int e = (h >> 7) & 0xFF;
    if (e >= 90 && e <= 160) cnt++;
  }
  sh[tid] = cnt;
  __syncthreads();
  for (int off = 128; off > 0; off >>= 1){
    if (tid < off) sh[tid] += sh[tid + off];
    __syncthreads();
  }
  if (tid == 0) g_isf32 = (sh[0] < 2458) ? 1 : 0;
}

// ---------------- zero deg/cursor
__global__ void k_zero(){
  int i = blockIdx.x * 256 + threadIdx.x;
  if (i < NN){ g_deg[i] = 0; g_cursor[i] = 0; }
}

// ---------------- all 6 weight transposes in ONE launch
__device__ __forceinline__ void xp_one(const void* W, unsigned short* Wt, int idx,
                                       int K, int Nc, int Kpad, int isf32){
  int n = idx / Kpad;
  int k = idx - n * Kpad;
  float v = 0.f;
  if (n < Nc && k < K) v = ld_in(W, k * Nc + n, isf32);
  Wt[idx] = f2b(v);
}
__global__ void k_transpose_all(const void* W1, const void* W2, const void* Wself,
                                const void* Wrel, const void* c1W, const void* c2W){
  int idx = blockIdx.x * 256 + threadIdx.x;
  const int isf32 = g_isf32;
  if (idx < 57344){ xp_one(W1, g_W1t, idx, 500, 100, 512, isf32); return; }
  idx -= 57344;
  if (idx < 14336){ xp_one(W2,    g_W2t,    idx, 100, 100, 128, isf32); return; }
  idx -= 14336;
  if (idx < 14336){ xp_one(Wself, g_WselfT, idx, 100, 100, 128, isf32); return; }
  idx -= 14336;
  if (idx < 14336){ xp_one(Wrel,  g_WrelT,  idx, 100, 100, 128, isf32); return; }
  idx -= 14336;
  if (idx < 14336){ xp_one(c1W,   g_c1Wt,   idx, 100, 100, 128, isf32); return; }
  idx -= 14336;
  if (idx < 8192){  xp_one(c2W,   g_c2Wt,   idx, 100, 64,  128, isf32); }
}

// ---------------- degree histogram
__global__ void k_deg(const int* __restrict__ tgt){
  int e = blockIdx.x * 256 + threadIdx.x;
  if (e < NE) atomicAdd(&g_deg[tgt[e]], 1);
}

// ---------------- two-level scan (scan1 fuses dinv)
__global__ __launch_bounds__(256) void k_scan1(){
  __shared__ int sh[256];
  int t = threadIdx.x;
  int i = blockIdx.x * 256 + t;
  int val = (i < NN) ? g_deg[i] : 0;
  sh[t] = val;
  __syncthreads();
#pragma unroll
  for (int off = 1; off < 256; off <<= 1){
    int v = (t >= off) ? sh[t - off] : 0;
    __syncthreads();
    sh[t] += v;
    __syncthreads();
  }
  if (i < NN){
    g_rowptr[i] = sh[t] - val;
    g_dinv[i] = rsqrtf((float)(val + 1));
  }
  if (t == 255) g_partial[blockIdx.x] = sh[255];
}
__global__ __launch_bounds__(256) void k_scan2(){
  __shared__ int sh[256];
  int t = threadIdx.x;
  int val = (t < SCAN_B) ? g_partial[t] : 0;
  sh[t] = val;
  __syncthreads();
#pragma unroll
  for (int off = 1; off < 256; off <<= 1){
    int v = (t >= off) ? sh[t - off] : 0;
    __syncthreads();
    sh[t] += v;
    __syncthreads();
  }
  if (t < SCAN_B) g_partial[t] = sh[t] - val;
  if (t == 255) g_rowptr[NN] = sh[255];
}
__global__ __launch_bounds__(256) void k_scan3(){
  int i = blockIdx.x * 256 + threadIdx.x;
  if (i < NN) g_rowptr[i] += g_partial[blockIdx.x];
}

// ---------------- CSR fill
__global__ void k_fill(const int* __restrict__ src, const int* __restrict__ tgt){
  int e = blockIdx.x * 256 + threadIdx.x;
  if (e >= NE) return;
  int t = tgt[e];
  int pos = g_rowptr[t] + atomicAdd(&g_cursor[t], 1);
  g_colidx[pos] = src[e];
}

// ---------------- gather-aggregate, high-MLP version.
// 16 lanes per node (ushort8 = 16B/lane), 4 nodes/wave, edge loop unrolled x4
// with 4 independent accumulator sets -> 16 outstanding row fetches per wave.
// MODE 0: plain sum from bufB (RGCN). MODE 1: normalized from bufC. MODE 2: normalized from bufB.
template<int MODE>
__global__ __launch_bounds__(256) void k_agg(){
  const unsigned short* x = (MODE == 1) ? g_bufC : g_bufB;
  int node = blockIdx.x * 16 + (threadIdx.x >> 4);
  if (node >= NN) return;
  const int c8 = (threadIdx.x & 15) * 8;

  float wt = (MODE != 0) ? g_dinv[node] : 1.f;
  float a[4][8];
#pragma unroll
  for (int j = 0; j < 4; j++)
#pragma unroll
    for (int k = 0; k < 8; k++) a[j][k] = 0.f;

  int p0 = g_rowptr[node], p1 = g_rowptr[node + 1];
  for (int p = p0; p < p1; p += 4){
    int   sj[4]; float wj[4];
#pragma unroll
    for (int j = 0; j < 4; j++){
      bool ok = (p + j) < p1;
      sj[j] = ok ? g_colidx[p + j] : node;
      wj[j] = ok ? ((MODE != 0) ? g_dinv[sj[j]] * wt : 1.f) : 0.f;
    }
    ushort8 r[4];
#pragma unroll
    for (int j = 0; j < 4; j++)
      r[j] = *reinterpret_cast<const ushort8*>(&x[(size_t)sj[j] * 128 + c8]);
#pragma unroll
    for (int j = 0; j < 4; j++)
#pragma unroll
      for (int k = 0; k < 8; k++) a[j][k] += wj[j] * b2f((unsigned short)r[j][k]);
  }
  if (MODE != 0){
    float ws = wt * wt;
    ushort8 sv = *reinterpret_cast<const ushort8*>(&x[(size_t)node * 128 + c8]);
#pragma unroll
    for (int k = 0; k < 8; k++) a[0][k] += ws * b2f((unsigned short)sv[k]);
  }
  ushort8 o;
#pragma unroll
  for (int k = 0; k < 8; k++)
    o[k] = f2b(a[0][k] + a[1][k] + a[2][k] + a[3][k]);
  *reinterpret_cast<ushort8*>(&g_bufA[(size_t)node * 128 + c8]) = o;
}

// ---------------- GEMM + bias + LayerNorm + ReLU
// SEL 0: A = data_x (raw input, f32 or bf16; conversion fused), K 500->512, out=bufA
// SEL 1: A = g_bufA [N,128] bf16, out=bufB
template<int SEL>
__global__ __launch_bounds__(256) void k_gemm_ln(const void* __restrict__ Aext,
    const void* __restrict__ bias, const void* __restrict__ gamma,
    const void* __restrict__ beta){
  constexpr int KPAD = (SEL == 0) ? 512 : 128;
  const unsigned short* Bt = (SEL == 0) ? g_W1t : g_W2t;
  unsigned short* out      = (SEL == 0) ? g_bufA : g_bufB;
  const int isf32 = g_isf32;

  const int wave = threadIdx.x >> 6, lane = threadIdx.x & 63;
  const int m = lane & 15, q = lane >> 4;
  const int row0 = (blockIdx.x * 4 + wave) * 16;
  if (row0 >= NN) return;
  f32x4 acc[7] = {};
  constexpr int CHN = KPAD / 32;

  if (SEL == 0 && isf32){
    // fused f32 -> bf16 A-load (rows: 500 floats = 2000B stride, 16B aligned)
    const float* arow = (const float*)Aext + (size_t)(row0 + m) * 500;
#pragma unroll
    for (int c = 0; c < CHN; c++){
      const int k0 = c * 32 + q * 8;
      short8 a;
      if (k0 + 8 <= 500){
        f32x4 lo = *reinterpret_cast<const f32x4*>(arow + k0);
        f32x4 hi = *reinterpret_cast<const f32x4*>(arow + k0 + 4);
        short8 t8 = {(short)f2b(lo[0]), (short)f2b(lo[1]), (short)f2b(lo[2]), (short)f2b(lo[3]),
                     (short)f2b(hi[0]), (short)f2b(hi[1]), (short)f2b(hi[2]), (short)f2b(hi[3])};
        a = t8;
      } else {
        short8 t8 = {0,0,0,0,0,0,0,0};
#pragma unroll
        for (int j = 0; j < 8; j++) if (k0 + j < 500) t8[j] = (short)f2b(arow[k0 + j]);
        a = t8;
      }
#pragma unroll
      for (int t = 0; t < 7; t++){
        short8 b = *reinterpret_cast<const short8*>(Bt + (size_t)(t * 16 + m) * KPAD + k0);
        acc[t] = MFMA16x16x32(a, b, acc[t], 0, 0, 0);
      }
    }
  } else if (SEL == 0){
    // bf16 input fallback (rows: 500 halves = 1000B stride, 8B aligned)
    const unsigned short* arow = (const unsigned short*)Aext + (size_t)(row0 + m) * 500;
#pragma unroll
    for (int c = 0; c < CHN; c++){
      const int k0 = c * 32 + q * 8;
      short8 a;
      if (k0 + 8 <= 500){
        ushort4 lo = *reinterpret_cast<const ushort4*>(arow + k0);
        ushort4 hi = *reinterpret_cast<const ushort4*>(arow + k0 + 4);
        short8 t8 = {(short)lo.x, (short)lo.y, (short)lo.z, (short)lo.w,
                     (short)hi.x, (short)hi.y, (short)hi.z, (short)hi.w};
        a = t8;
      } else {
        short8 t8 = {0,0,0,0,0,0,0,0};
#pragma unroll
        for (int j = 0; j < 8; j++) if (k0 + j < 500) t8[j] = (short)arow[k0 + j];
        a = t8;
      }
#pragma unroll
      for (int t = 0; t < 7; t++){
        short8 b = *reinterpret_cast<const short8*>(Bt + (size_t)(t * 16 + m) * KPAD + k0);
        acc[t] = MFMA16x16x32(a, b, acc[t], 0, 0, 0);
      }
    }
  } else {
    const unsigned short* arow = g_bufA + (size_t)(row0 + m) * KPAD;
#pragma unroll
    for (int c = 0; c < CHN; c++){
      const int k0 = c * 32 + q * 8;
      short8 a = *reinterpret_cast<const short8*>(arow + k0);
#pragma unroll
      for (int t = 0; t < 7; t++){
        short8 b = *reinterpret_cast<const short8*>(Bt + (size_t)(t * 16 + m) * KPAD + k0);
        acc[t] = MFMA16x16x32(a, b, acc[t], 0, 0, 0);
      }
    }
  }

  float bf_[7], gf_[7], ef_[7];
#pragma unroll
  for (int t = 0; t < 7; t++){
    int col = t * 16 + m;
    bool ok = col < 100;
    bf_[t] = ok ? ld_in(bias, col, isf32)  : 0.f;
    gf_[t] = ok ? ld_in(gamma, col, isf32) : 0.f;
    ef_[t] = ok ? ld_in(beta, col, isf32)  : 0.f;
  }
#pragma unroll
  for (int r = 0; r < 4; r++){
    float vals[7], s1 = 0.f, s2 = 0.f;
#pragma unroll
    for (int t = 0; t < 7; t++){
      int col = t * 16 + m;
      float v = (col < 100) ? (acc[t][r] + bf_[t]) : 0.f;
      vals[t] = v; s1 += v; s2 += v * v;
    }
#pragma unroll
    for (int msk = 1; msk < 16; msk <<= 1){
      s1 += __shfl_xor(s1, msk, 64);
      s2 += __shfl_xor(s2, msk, 64);
    }
    float mu = s1 * 0.01f;
    float var = fmaxf(s2 * 0.01f - mu * mu, 0.f);
    float rstd = rsqrtf(var + 1e-5f);
    unsigned short* orow = out + (size_t)(row0 + q * 4 + r) * 128;
#pragma unroll
    for (int t = 0; t < 7; t++){
      int col = t * 16 + m;
      float y = fmaxf((vals[t] - mu) * rstd * gf_[t] + ef_[t], 0.f);
      orow[col] = f2b((col < 100) ? y : 0.f);
    }
    orow[112 + m] = 0;
  }
}

// ---------------- (A1@B1t [+ A2@B2t]) + bias, ReLU. K=128.
template<int SEL>
__global__ __launch_bounds__(256) void k_gemm_bias_relu(const void* __restrict__ bias){
  const unsigned short* A1  = (SEL == 0) ? g_bufB : g_bufA;
  const unsigned short* B1t = (SEL == 0) ? g_WselfT : g_c1Wt;
  unsigned short* out       = (SEL == 0) ? g_bufC : g_bufB;
  const int isf32 = g_isf32;

  const int wave = threadIdx.x >> 6, lane = threadIdx.x & 63;
  const int m = lane & 15, q = lane >> 4;
  const int row0 = (blockIdx.x * 4 + wave) * 16;
  if (row0 >= NN) return;
  f32x4 acc[7] = {};
  const unsigned short* a1row = A1 + (size_t)(row0 + m) * 128;
#pragma unroll
  for (int c = 0; c < 4; c++){
    const int k0 = c * 32 + q * 8;
    short8 a = *reinterpret_cast<const short8*>(a1row + k0);
#pragma unroll
    for (int t = 0; t < 7; t++){
      short8 b = *reinterpret_cast<const short8*>(B1t + (size_t)(t * 16 + m) * 128 + k0);
      acc[t] = MFMA16x16x32(a, b, acc[t], 0, 0, 0);
    }
  }
  if (SEL == 0){
    const unsigned short* a2row = g_bufA + (size_t)(row0 + m) * 128;
#pragma unroll
    for (int c = 0; c < 4; c++){
      const int k0 = c * 32 + q * 8;
      short8 a = *reinterpret_cast<const short8*>(a2row + k0);
#pragma unroll
      for (int t = 0; t < 7; t++){
        short8 b = *reinterpret_cast<const short8*>(g_WrelT + (size_t)(t * 16 + m) * 128 + k0);
        acc[t] = MFMA16x16x32(a, b, acc[t], 0, 0, 0);
      }
    }
  }
  float bf_[7];
#pragma unroll
  for (int t = 0; t < 7; t++){
    int col = t * 16 + m;
    bf_[t] = (col < 100) ? ld_in(bias, col, isf32) : 0.f;
  }
#pragma unroll
  for (int r = 0; r < 4; r++){
    unsigned short* orow = out + (size_t)(row0 + q * 4 + r) * 128;
#pragma unroll
    for (int t = 0; t < 7; t++){
      int col = t * 16 + m;
      float y = fmaxf(acc[t][r] + bf_[t], 0.f);
      orow[col] = f2b((col < 100) ? y : 0.f);
    }
    orow[112 + m] = 0;
  }
}

// ---------------- bufA@c2Wt + bias -> log_softmax -> d_out [N,64]
__global__ __launch_bounds__(256) void k_gemm_lsm(const void* __restrict__ bias,
                                                  void* __restrict__ outv){
  const int isf32 = g_isf32;
  const int wave = threadIdx.x >> 6, lane = threadIdx.x & 63;
  const int m = lane & 15, q = lane >> 4;
  const int row0 = (blockIdx.x * 4 + wave) * 16;
  if (row0 >= NN) return;
  f32x4 acc[4] = {};
  const unsigned short* arow = g_bufA + (size_t)(row0 + m) * 128;
#pragma unroll
  for (int c = 0; c < 4; c++){
    const int k0 = c * 32 + q * 8;
    short8 a = *reinterpret_cast<const short8*>(arow + k0);
#pragma unroll
    for (int t = 0; t < 4; t++){
      short8 b = *reinterpret_cast<const short8*>(g_c2Wt + (size_t)(t * 16 + m) * 128 + k0);
      acc[t] = MFMA16x16x32(a, b, acc[t], 0, 0, 0);
    }
  }
  float bf_[4];
#pragma unroll
  for (int t = 0; t < 4; t++) bf_[t] = ld_in(bias, t * 16 + m, isf32);
#pragma unroll
  for (int r = 0; r < 4; r++){
    float vals[4], mx = -1e30f;
#pragma unroll
    for (int t = 0; t < 4; t++){
      float v = acc[t][r] + bf_[t];
      vals[t] = v; mx = fmaxf(mx, v);
    }
#pragma unroll
    for (int msk = 1; msk < 16; msk <<= 1) mx = fmaxf(mx, __shfl_xor(mx, msk, 64));
    float se = 0.f;
#pragma unroll
    for (int t = 0; t < 4; t++) se += expf(vals[t] - mx);
#pragma unroll
    for (int msk = 1; msk < 16; msk <<= 1) se += __shfl_xor(se, msk, 64);
    float lse = logf(se);
    size_t ro = (size_t)(row0 + q * 4 + r) * 64;
    if (isf32){
      float* orow = (float*)outv + ro;
#pragma unroll
      for (int t = 0; t < 4; t++) orow[t * 16 + m] = vals[t] - mx - lse;
    } else {
      unsigned short* orow = (unsigned short*)outv + ro;
#pragma unroll
      for (int t = 0; t < 4; t++) orow[t * 16 + m] = f2b(vals[t] - mx - lse);
    }
  }
}

extern "C" void kernel_launch(void* const* d_in, const int* in_sizes, int n_in,
                              void* d_out, int out_size, void* d_ws, size_t ws_size,
                              hipStream_t stream){
  (void)in_sizes; (void)n_in; (void)out_size; (void)d_ws; (void)ws_size;
  const void* data_x = d_in[0];
  const int* ei = (const int*)d_in[1];
  const int* src = ei;
  const int* tgt = ei + NE;
  const void *W1 = d_in[3], *b1 = d_in[4], *gm1 = d_in[5], *be1 = d_in[6];
  const void *W2 = d_in[7], *b2 = d_in[8], *gm2 = d_in[9], *be2 = d_in[10];
  const void *Wrel = d_in[11], *Wself = d_in[12], *rb = d_in[13];
  const void *c1W = d_in[14], *c1b = d_in[15];
  const void *c2W = d_in[16], *c2b = d_in[17];

  k_detect<<<1, 256, 0, stream>>>((const unsigned short*)data_x);
  k_zero<<<(NN + 255) / 256, 256, 0, stream>>>();
  k_transpose_all<<<(122880 + 255) / 256, 256, 0, stream>>>(W1, W2, Wself, Wrel, c1W, c2W);

  k_deg<<<(NE + 255) / 256, 256, 0, stream>>>(tgt);
  k_scan1<<<SCAN_B, 256, 0, stream>>>();
  k_scan2<<<1, 256, 0, stream>>>();
  k_scan3<<<SCAN_B, 256, 0, stream>>>();
  k_fill<<<(NE + 255) / 256, 256, 0, stream>>>(src, tgt);

  const int GB = (NN / 16 + 3) / 4;   // 782 blocks, 4 waves x 16 rows
  const int GA = (NN + 15) / 16;      // 3125 blocks, 16 nodes/block
  k_gemm_ln<0><<<GB, 256, 0, stream>>>(data_x, b1, gm1, be1);  // data_x -> bufA
  k_gemm_ln<1><<<GB, 256, 0, stream>>>(nullptr, b2, gm2, be2); // bufA -> bufB
  k_agg<0><<<GA, 256, 0, stream>>>();                          // bufB -> bufA (RGCN sum)
  k_gemm_bias_relu<0><<<GB, 256, 0, stream>>>(rb);             // bufB@Wself + bufA@Wrel -> bufC
  k_agg<1><<<GA, 256, 0, stream>>>();                          // bufC -> bufA (GCN norm)
  k_gemm_bias_relu<1><<<GB, 256, 0, stream>>>(c1b);            // bufA@c1W -> bufB
  k_agg<2><<<GA, 256, 0, stream>>>();                          // bufB -> bufA (GCN norm)
  k_gemm_lsm<<<GB, 256, 0, stream>>>(c2b, d_out);
}

// Round 6
// 526.053 us; speedup vs baseline: 1.3616x; 1.0006x over previous
//
#include <hip/hip_runtime.h>
#include <hip/hip_bf16.h>

typedef __attribute__((ext_vector_type(8))) short short8;
typedef __attribute__((ext_vector_type(8))) unsigned short ushort8;
typedef __attribute__((ext_vector_type(4))) float f32x4;

static constexpr int NN = 50000;   // nodes
static constexpr int NE = 800000;  // edges
static constexpr int SCAN_B = 196; // ceil(NN/256)

#define MFMA16x16x32 __builtin_amdgcn_mfma_f32_16x16x32_bf16

__device__ __forceinline__ float b2f(unsigned short u){
  unsigned v = ((unsigned)u) << 16;
  return __builtin_bit_cast(float, v);
}
__device__ __forceinline__ unsigned short f2b(float f){
  unsigned x = __builtin_bit_cast(unsigned, f);
  unsigned r = (x + 0x7fffu + ((x >> 16) & 1u)) >> 16;  // RNE
  return (unsigned short)r;
}

// ---------------- static device scratch
__device__ __align__(256) int   g_isf32;
__device__ __align__(256) unsigned short g_W1t  [112 * 512];
__device__ __align__(256) unsigned short g_W2t  [112 * 128];
__device__ __align__(256) unsigned short g_WselfT[112 * 128];
__device__ __align__(256) unsigned short g_WrelT [112 * 128];
__device__ __align__(256) unsigned short g_c1Wt [112 * 128];
__device__ __align__(256) unsigned short g_c2Wt [64 * 128];
__device__ __align__(256) unsigned short g_bufA[(size_t)NN * 128];
__device__ __align__(256) unsigned short g_bufB[(size_t)NN * 128];
__device__ __align__(256) unsigned short g_bufC[(size_t)NN * 128];
__device__ __align__(256) int   g_deg[NN];
__device__ __align__(256) int   g_rowptr[NN + 1];
__device__ __align__(256) int   g_cursor[NN];
__device__ __align__(256) int   g_colidx[NE];
__device__ __align__(256) float g_dinv[NN];
__device__ __align__(256) int   g_partial[256];

__device__ __forceinline__ float ld_in(const void* p, int idx, int isf32){
  if (isf32) return ((const float*)p)[idx];
  return b2f(((const unsigned short*)p)[idx]);
}

// ---------------- dtype sniffer
__global__ void k_detect(const unsigned short* __restrict__ x){
  __shared__ int sh[256];
  int tid = threadIdx.x;
  int cnt = 0;
  for (int j = 0; j < 16; j++){
    unsigned short h = x[(size_t)(tid * 16 + j) * 2];
    int e = (h >> 7) & 0xFF;
    if (e >= 90 && e <= 160) cnt++;
  }
  sh[tid] = cnt;
  __syncthreads();
  for (int off = 128; off > 0; off >>= 1){
    if (tid < off) sh[tid] += sh[tid + off];
    __syncthreads();
  }
  if (tid == 0) g_isf32 = (sh[0] < 2458) ? 1 : 0;
}

// ---------------- zero deg/cursor
__global__ void k_zero(){
  int i = blockIdx.x * 256 + threadIdx.x;
  if (i < NN){ g_deg[i] = 0; g_cursor[i] = 0; }
}

// ---------------- all 6 weight transposes in ONE launch
__device__ __forceinline__ void xp_one(const void* W, unsigned short* Wt, int idx,
                                       int K, int Nc, int Kpad, int isf32){
  int n = idx / Kpad;
  int k = idx - n * Kpad;
  float v = 0.f;
  if (n < Nc && k < K) v = ld_in(W, k * Nc + n, isf32);
  Wt[idx] = f2b(v);
}
__global__ void k_transpose_all(const void* W1, const void* W2, const void* Wself,
                                const void* Wrel, const void* c1W, const void* c2W){
  int idx = blockIdx.x * 256 + threadIdx.x;
  const int isf32 = g_isf32;
  if (idx < 57344){ xp_one(W1, g_W1t, idx, 500, 100, 512, isf32); return; }
  idx -= 57344;
  if (idx < 14336){ xp_one(W2,    g_W2t,    idx, 100, 100, 128, isf32); return; }
  idx -= 14336;
  if (idx < 14336){ xp_one(Wself, g_WselfT, idx, 100, 100, 128, isf32); return; }
  idx -= 14336;
  if (idx < 14336){ xp_one(Wrel,  g_WrelT,  idx, 100, 100, 128, isf32); return; }
  idx -= 14336;
  if (idx < 14336){ xp_one(c1W,   g_c1Wt,   idx, 100, 100, 128, isf32); return; }
  idx -= 14336;
  if (idx < 8192){  xp_one(c2W,   g_c2Wt,   idx, 100, 64,  128, isf32); }
}

// ---------------- degree histogram
__global__ void k_deg(const int* __restrict__ tgt){
  int e = blockIdx.x * 256 + threadIdx.x;
  if (e < NE) atomicAdd(&g_deg[tgt[e]], 1);
}

// ---------------- two-level scan (scan1 fuses dinv)
__global__ __launch_bounds__(256) void k_scan1(){
  __shared__ int sh[256];
  int t = threadIdx.x;
  int i = blockIdx.x * 256 + t;
  int val = (i < NN) ? g_deg[i] : 0;
  sh[t] = val;
  __syncthreads();
#pragma unroll
  for (int off = 1; off < 256; off <<= 1){
    int v = (t >= off) ? sh[t - off] : 0;
    __syncthreads();
    sh[t] += v;
    __syncthreads();
  }
  if (i < NN){
    g_rowptr[i] = sh[t] - val;
    g_dinv[i] = rsqrtf((float)(val + 1));
  }
  if (t == 255) g_partial[blockIdx.x] = sh[255];
}
__global__ __launch_bounds__(256) void k_scan2(){
  __shared__ int sh[256];
  int t = threadIdx.x;
  int val = (t < SCAN_B) ? g_partial[t] : 0;
  sh[t] = val;
  __syncthreads();
#pragma unroll
  for (int off = 1; off < 256; off <<= 1){
    int v = (t >= off) ? sh[t - off] : 0;
    __syncthreads();
    sh[t] += v;
    __syncthreads();
  }
  if (t < SCAN_B) g_partial[t] = sh[t] - val;
  if (t == 255) g_rowptr[NN] = sh[255];
}
__global__ __launch_bounds__(256) void k_scan3(){
  int i = blockIdx.x * 256 + threadIdx.x;
  if (i < NN) g_rowptr[i] += g_partial[blockIdx.x];
}

// ---------------- CSR fill
__global__ void k_fill(const int* __restrict__ src, const int* __restrict__ tgt){
  int e = blockIdx.x * 256 + threadIdx.x;
  if (e >= NE) return;
  int t = tgt[e];
  int pos = g_rowptr[t] + atomicAdd(&g_cursor[t], 1);
  g_colidx[pos] = src[e];
}

// ---------------- gather-aggregate, high-MLP (16 lanes/node, x4 unroll)
template<int MODE>
__global__ __launch_bounds__(256) void k_agg(){
  const unsigned short* x = (MODE == 1) ? g_bufC : g_bufB;
  int node = blockIdx.x * 16 + (threadIdx.x >> 4);
  if (node >= NN) return;
  const int c8 = (threadIdx.x & 15) * 8;

  float wt = (MODE != 0) ? g_dinv[node] : 1.f;
  float a[4][8];
#pragma unroll
  for (int j = 0; j < 4; j++)
#pragma unroll
    for (int k = 0; k < 8; k++) a[j][k] = 0.f;

  int p0 = g_rowptr[node], p1 = g_rowptr[node + 1];
  for (int p = p0; p < p1; p += 4){
    int   sj[4]; float wj[4];
#pragma unroll
    for (int j = 0; j < 4; j++){
      bool ok = (p + j) < p1;
      sj[j] = ok ? g_colidx[p + j] : node;
      wj[j] = ok ? ((MODE != 0) ? g_dinv[sj[j]] * wt : 1.f) : 0.f;
    }
    ushort8 r[4];
#pragma unroll
    for (int j = 0; j < 4; j++)
      r[j] = *reinterpret_cast<const ushort8*>(&x[(size_t)sj[j] * 128 + c8]);
#pragma unroll
    for (int j = 0; j < 4; j++)
#pragma unroll
      for (int k = 0; k < 8; k++) a[j][k] += wj[j] * b2f((unsigned short)r[j][k]);
  }
  if (MODE != 0){
    float ws = wt * wt;
    ushort8 sv = *reinterpret_cast<const ushort8*>(&x[(size_t)node * 128 + c8]);
#pragma unroll
    for (int k = 0; k < 8; k++) a[0][k] += ws * b2f((unsigned short)sv[k]);
  }
  ushort8 o;
#pragma unroll
  for (int k = 0; k < 8; k++)
    o[k] = f2b(a[0][k] + a[1][k] + a[2][k] + a[3][k]);
  *reinterpret_cast<ushort8*>(&g_bufA[(size_t)node * 128 + c8]) = o;
}

// ---------------- GEMM1 (data_x [N,500] -> bufA), LDS-staged coalesced A.
// Block = 64 rows, 4 chunks of K=128: 256 threads stage 64x128 f32 coalesced
// (f32->bf16 fused), waves MFMA from LDS. Row stride 136 shorts (272B: 16B-
// aligned; uniform 8-round LDS reads = bandwidth floor, no hotspot).
__global__ __launch_bounds__(256) void k_gemm1_ln(const void* __restrict__ Aext,
    const void* __restrict__ bias, const void* __restrict__ gamma,
    const void* __restrict__ beta){
  __shared__ unsigned short sA[64 * 136];
  const int tid = threadIdx.x;
  const int wave = tid >> 6, lane = tid & 63;
  const int m = lane & 15, q = lane >> 4;
  const int rowblk = blockIdx.x * 64;
  const int isf32 = g_isf32;
  const int srow = tid >> 5;        // 0..7
  const int scol = (tid & 31) * 4;  // f32-unit col within chunk
  f32x4 acc[7] = {};

  for (int kc = 0; kc < 4; kc++){
    __syncthreads();
#pragma unroll
    for (int ps = 0; ps < 8; ps++){
      int r = ps * 8 + srow;
      int grow = rowblk + r;
      int gcol = kc * 128 + scol;
      ushort4 vb = {0, 0, 0, 0};
      if (grow < NN && gcol + 4 <= 500){   // 500 % 4 == 0: all-or-nothing
        if (isf32){
          f32x4 v = *reinterpret_cast<const f32x4*>((const float*)Aext + (size_t)grow * 500 + gcol);
          vb.x = f2b(v[0]); vb.y = f2b(v[1]); vb.z = f2b(v[2]); vb.w = f2b(v[3]);
        } else {
          vb = *reinterpret_cast<const ushort4*>((const unsigned short*)Aext + (size_t)grow * 500 + gcol);
        }
      }
      *reinterpret_cast<ushort4*>(&sA[r * 136 + scol]) = vb;
    }
    __syncthreads();
#pragma unroll
    for (int c = 0; c < 4; c++){
      int k0 = c * 32 + q * 8;
      short8 a = *reinterpret_cast<const short8*>(&sA[(wave * 16 + m) * 136 + k0]);
      int gk0 = kc * 128 + k0;
#pragma unroll
      for (int t = 0; t < 7; t++){
        short8 b = *reinterpret_cast<const short8*>(g_W1t + (size_t)(t * 16 + m) * 512 + gk0);
        acc[t] = MFMA16x16x32(a, b, acc[t], 0, 0, 0);
      }
    }
  }

  // epilogue: +bias, LN over 100 cols, ReLU -> g_bufA [N,128]
  float bf_[7], gf_[7], ef_[7];
#pragma unroll
  for (int t = 0; t < 7; t++){
    int col = t * 16 + m;
    bool ok = col < 100;
    bf_[t] = ok ? ld_in(bias, col, isf32)  : 0.f;
    gf_[t] = ok ? ld_in(gamma, col, isf32) : 0.f;
    ef_[t] = ok ? ld_in(beta, col, isf32)  : 0.f;
  }
  const int row0 = rowblk + wave * 16;
#pragma unroll
  for (int r = 0; r < 4; r++){
    float vals[7], s1 = 0.f, s2 = 0.f;
#pragma unroll
    for (int t = 0; t < 7; t++){
      int col = t * 16 + m;
      float v = (col < 100) ? (acc[t][r] + bf_[t]) : 0.f;
      vals[t] = v; s1 += v; s2 += v * v;
    }
#pragma unroll
    for (int msk = 1; msk < 16; msk <<= 1){
      s1 += __shfl_xor(s1, msk, 64);
      s2 += __shfl_xor(s2, msk, 64);
    }
    float mu = s1 * 0.01f;
    float var = fmaxf(s2 * 0.01f - mu * mu, 0.f);
    float rstd = rsqrtf(var + 1e-5f);
    int row = row0 + q * 4 + r;
    if (row < NN){
      unsigned short* orow = g_bufA + (size_t)row * 128;
#pragma unroll
      for (int t = 0; t < 7; t++){
        int col = t * 16 + m;
        float y = fmaxf((vals[t] - mu) * rstd * gf_[t] + ef_[t], 0.f);
        orow[col] = f2b((col < 100) ? y : 0.f);
      }
      orow[112 + m] = 0;
    }
  }
}

// ---------------- GEMM2 + LN + ReLU (bufA [N,128] @ W2t -> bufB)
__global__ __launch_bounds__(256) void k_gemm2_ln(const void* __restrict__ bias,
    const void* __restrict__ gamma, const void* __restrict__ beta){
  const int isf32 = g_isf32;
  const int wave = threadIdx.x >> 6, lane = threadIdx.x & 63;
  const int m = lane & 15, q = lane >> 4;
  const int row0 = (blockIdx.x * 4 + wave) * 16;
  if (row0 >= NN) return;
  f32x4 acc[7] = {};
  const unsigned short* arow = g_bufA + (size_t)(row0 + m) * 128;
#pragma unroll
  for (int c = 0; c < 4; c++){
    const int k0 = c * 32 + q * 8;
    short8 a = *reinterpret_cast<const short8*>(arow + k0);
#pragma unroll
    for (int t = 0; t < 7; t++){
      short8 b = *reinterpret_cast<const short8*>(g_W2t + (size_t)(t * 16 + m) * 128 + k0);
      acc[t] = MFMA16x16x32(a, b, acc[t], 0, 0, 0);
    }
  }
  float bf_[7], gf_[7], ef_[7];
#pragma unroll
  for (int t = 0; t < 7; t++){
    int col = t * 16 + m;
    bool ok = col < 100;
    bf_[t] = ok ? ld_in(bias, col, isf32)  : 0.f;
    gf_[t] = ok ? ld_in(gamma, col, isf32) : 0.f;
    ef_[t] = ok ? ld_in(beta, col, isf32)  : 0.f;
  }
#pragma unroll
  for (int r = 0; r < 4; r++){
    float vals[7], s1 = 0.f, s2 = 0.f;
#pragma unroll
    for (int t = 0; t < 7; t++){
      int col = t * 16 + m;
      float v = (col < 100) ? (acc[t][r] + bf_[t]) : 0.f;
      vals[t] = v; s1 += v; s2 += v * v;
    }
#pragma unroll
    for (int msk = 1; msk < 16; msk <<= 1){
      s1 += __shfl_xor(s1, msk, 64);
      s2 += __shfl_xor(s2, msk, 64);
    }
    float mu = s1 * 0.01f;
    float var = fmaxf(s2 * 0.01f - mu * mu, 0.f);
    float rstd = rsqrtf(var + 1e-5f);
    unsigned short* orow = g_bufB + (size_t)(row0 + q * 4 + r) * 128;
#pragma unroll
    for (int t = 0; t < 7; t++){
      int col = t * 16 + m;
      float y = fmaxf((vals[t] - mu) * rstd * gf_[t] + ef_[t], 0.f);
      orow[col] = f2b((col < 100) ? y : 0.f);
    }
    orow[112 + m] = 0;
  }
}

// ---------------- (A1@B1t [+ A2@B2t]) + bias, ReLU. K=128.
template<int SEL>
__global__ __launch_bounds__(256) void k_gemm_bias_relu(const void* __restrict__ bias){
  const unsigned short* A1  = (SEL == 0) ? g_bufB : g_bufA;
  const unsigned short* B1t = (SEL == 0) ? g_WselfT : g_c1Wt;
  unsigned short* out       = (SEL == 0) ? g_bufC : g_bufB;
  const int isf32 = g_isf32;

  const int wave = threadIdx.x >> 6, lane = threadIdx.x & 63;
  const int m = lane & 15, q = lane >> 4;
  const int row0 = (blockIdx.x * 4 + wave) * 16;
  if (row0 >= NN) return;
  f32x4 acc[7] = {};
  const unsigned short* a1row = A1 + (size_t)(row0 + m) * 128;
#pragma unroll
  for (int c = 0; c < 4; c++){
    const int k0 = c * 32 + q * 8;
    short8 a = *reinterpret_cast<const short8*>(a1row + k0);
#pragma unroll
    for (int t = 0; t < 7; t++){
      short8 b = *reinterpret_cast<const short8*>(B1t + (size_t)(t * 16 + m) * 128 + k0);
      acc[t] = MFMA16x16x32(a, b, acc[t], 0, 0, 0);
    }
  }
  if (SEL == 0){
    const unsigned short* a2row = g_bufA + (size_t)(row0 + m) * 128;
#pragma unroll
    for (int c = 0; c < 4; c++){
      const int k0 = c * 32 + q * 8;
      short8 a = *reinterpret_cast<const short8*>(a2row + k0);
#pragma unroll
      for (int t = 0; t < 7; t++){
        short8 b = *reinterpret_cast<const short8*>(g_WrelT + (size_t)(t * 16 + m) * 128 + k0);
        acc[t] = MFMA16x16x32(a, b, acc[t], 0, 0, 0);
      }
    }
  }
  float bf_[7];
#pragma unroll
  for (int t = 0; t < 7; t++){
    int col = t * 16 + m;
    bf_[t] = (col < 100) ? ld_in(bias, col, isf32) : 0.f;
  }
#pragma unroll
  for (int r = 0; r < 4; r++){
    unsigned short* orow = out + (size_t)(row0 + q * 4 + r) * 128;
#pragma unroll
    for (int t = 0; t < 7; t++){
      int col = t * 16 + m;
      float y = fmaxf(acc[t][r] + bf_[t], 0.f);
      orow[col] = f2b((col < 100) ? y : 0.f);
    }
    orow[112 + m] = 0;
  }
}

// ---------------- bufA@c2Wt + bias -> log_softmax -> d_out [N,64]
__global__ __launch_bounds__(256) void k_gemm_lsm(const void* __restrict__ bias,
                                                  void* __restrict__ outv){
  const int isf32 = g_isf32;
  const int wave = threadIdx.x >> 6, lane = threadIdx.x & 63;
  const int m = lane & 15, q = lane >> 4;
  const int row0 = (blockIdx.x * 4 + wave) * 16;
  if (row0 >= NN) return;
  f32x4 acc[4] = {};
  const unsigned short* arow = g_bufA + (size_t)(row0 + m) * 128;
#pragma unroll
  for (int c = 0; c < 4; c++){
    const int k0 = c * 32 + q * 8;
    short8 a = *reinterpret_cast<const short8*>(arow + k0);
#pragma unroll
    for (int t = 0; t < 4; t++){
      short8 b = *reinterpret_cast<const short8*>(g_c2Wt + (size_t)(t * 16 + m) * 128 + k0);
      acc[t] = MFMA16x16x32(a, b, acc[t], 0, 0, 0);
    }
  }
  float bf_[4];
#pragma unroll
  for (int t = 0; t < 4; t++) bf_[t] = ld_in(bias, t * 16 + m, isf32);
#pragma unroll
  for (int r = 0; r < 4; r++){
    float vals[4], mx = -1e30f;
#pragma unroll
    for (int t = 0; t < 4; t++){
      float v = acc[t][r] + bf_[t];
      vals[t] = v; mx = fmaxf(mx, v);
    }
#pragma unroll
    for (int msk = 1; msk < 16; msk <<= 1) mx = fmaxf(mx, __shfl_xor(mx, msk, 64));
    float se = 0.f;
#pragma unroll
    for (int t = 0; t < 4; t++) se += expf(vals[t] - mx);
#pragma unroll
    for (int msk = 1; msk < 16; msk <<= 1) se += __shfl_xor(se, msk, 64);
    float lse = logf(se);
    size_t ro = (size_t)(row0 + q * 4 + r) * 64;
    if (isf32){
      float* orow = (float*)outv + ro;
#pragma unroll
      for (int t = 0; t < 4; t++) orow[t * 16 + m] = vals[t] - mx - lse;
    } else {
      unsigned short* orow = (unsigned short*)outv + ro;
#pragma unroll
      for (int t = 0; t < 4; t++) orow[t * 16 + m] = f2b(vals[t] - mx - lse);
    }
  }
}

extern "C" void kernel_launch(void* const* d_in, const int* in_sizes, int n_in,
                              void* d_out, int out_size, void* d_ws, size_t ws_size,
                              hipStream_t stream){
  (void)in_sizes; (void)n_in; (void)out_size; (void)d_ws; (void)ws_size;
  const void* data_x = d_in[0];
  const int* ei = (const int*)d_in[1];
  const int* src = ei;
  const int* tgt = ei + NE;
  const void *W1 = d_in[3], *b1 = d_in[4], *gm1 = d_in[5], *be1 = d_in[6];
  const void *W2 = d_in[7], *b2 = d_in[8], *gm2 = d_in[9], *be2 = d_in[10];
  const void *Wrel = d_in[11], *Wself = d_in[12], *rb = d_in[13];
  const void *c1W = d_in[14], *c1b = d_in[15];
  const void *c2W = d_in[16], *c2b = d_in[17];

  k_detect<<<1, 256, 0, stream>>>((const unsigned short*)data_x);
  k_zero<<<(NN + 255) / 256, 256, 0, stream>>>();
  k_transpose_all<<<(122880 + 255) / 256, 256, 0, stream>>>(W1, W2, Wself, Wrel, c1W, c2W);

  k_deg<<<(NE + 255) / 256, 256, 0, stream>>>(tgt);
  k_scan1<<<SCAN_B, 256, 0, stream>>>();
  k_scan2<<<1, 256, 0, stream>>>();
  k_scan3<<<SCAN_B, 256, 0, stream>>>();
  k_fill<<<(NE + 255) / 256, 256, 0, stream>>>(src, tgt);

  const int G64 = (NN + 63) / 64;     // 782 blocks, 64 rows each
  const int GA  = (NN + 15) / 16;     // 3125 blocks, 16 nodes/block
  k_gemm1_ln<<<G64, 256, 0, stream>>>(data_x, b1, gm1, be1);   // data_x -> bufA
  k_gemm2_ln<<<G64, 256, 0, stream>>>(b2, gm2, be2);           // bufA -> bufB
  k_agg<0><<<GA, 256, 0, stream>>>();                          // bufB -> bufA (RGCN sum)
  k_gemm_bias_relu<0><<<G64, 256, 0, stream>>>(rb);            // bufB@Wself + bufA@Wrel -> bufC
  k_agg<1><<<GA, 256, 0, stream>>>();                          // bufC -> bufA (GCN norm)
  k_gemm_bias_relu<1><<<G64, 256, 0, stream>>>(c1b);           // bufA@c1W -> bufB
  k_agg<2><<<GA, 256, 0, stream>>>();                          // bufB -> bufA (GCN norm)
  k_gemm_lsm<<<G64, 256, 0, stream>>>(c2b, d_out);
}

// Round 7
// 523.857 us; speedup vs baseline: 1.3673x; 1.0042x over previous
//
#include <hip/hip_runtime.h>
#include <hip/hip_bf16.h>

typedef __attribute__((ext_vector_type(8))) short short8;
typedef __attribute__((ext_vector_type(8))) unsigned short ushort8;
typedef __attribute__((ext_vector_type(4))) float f32x4;

static constexpr int NN = 50000;   // nodes
static constexpr int NE = 800000;  // edges
static constexpr int SCAN_B = 196; // ceil(NN/256)

#define MFMA16x16x32 __builtin_amdgcn_mfma_f32_16x16x32_bf16

__device__ __forceinline__ float b2f(unsigned short u){
  unsigned v = ((unsigned)u) << 16;
  return __builtin_bit_cast(float, v);
}
__device__ __forceinline__ unsigned short f2b(float f){
  unsigned x = __builtin_bit_cast(unsigned, f);
  unsigned r = (x + 0x7fffu + ((x >> 16) & 1u)) >> 16;  // RNE
  return (unsigned short)r;
}

// ---------------- static device scratch
__device__ __align__(256) int   g_isf32;
__device__ __align__(256) unsigned short g_W1t  [112 * 512];
__device__ __align__(256) unsigned short g_W2t  [112 * 128];
__device__ __align__(256) unsigned short g_WselfT[112 * 128];
__device__ __align__(256) unsigned short g_WrelT [112 * 128];
__device__ __align__(256) unsigned short g_c1Wt [112 * 128];
__device__ __align__(256) unsigned short g_c2Wt [64 * 128];
__device__ __align__(256) unsigned short g_bufA[(size_t)NN * 128];
__device__ __align__(256) unsigned short g_bufB[(size_t)NN * 128];
__device__ __align__(256) unsigned short g_bufC[(size_t)NN * 128];
__device__ __align__(256) int   g_deg[NN];
__device__ __align__(256) int   g_rowptr[NN + 1];
__device__ __align__(256) int   g_cursor[NN];
__device__ __align__(256) int   g_colidx[NE];
__device__ __align__(256) float g_dinv[NN];
__device__ __align__(256) int   g_partial[256];

__device__ __forceinline__ float ld_in(const void* p, int idx, int isf32){
  if (isf32) return ((const float*)p)[idx];
  return b2f(((const unsigned short*)p)[idx]);
}

// ---------------- dtype sniffer
__global__ void k_detect(const unsigned short* __restrict__ x){
  __shared__ int sh[256];
  int tid = threadIdx.x;
  int cnt = 0;
  for (int j = 0; j < 16; j++){
    unsigned short h = x[(size_t)(tid * 16 + j) * 2];
    int e = (h >> 7) & 0xFF;
    if (e >= 90 && e <= 160) cnt++;
  }
  sh[tid] = cnt;
  __syncthreads();
  for (int off = 128; off > 0; off >>= 1){
    if (tid < off) sh[tid] += sh[tid + off];
    __syncthreads();
  }
  if (tid == 0) g_isf32 = (sh[0] < 2458) ? 1 : 0;
}

// ---------------- zero deg/cursor
__global__ void k_zero(){
  int i = blockIdx.x * 256 + threadIdx.x;
  if (i < NN){ g_deg[i] = 0; g_cursor[i] = 0; }
}

// ---------------- all 6 weight transposes in ONE launch
__device__ __forceinline__ void xp_one(const void* W, unsigned short* Wt, int idx,
                                       int K, int Nc, int Kpad, int isf32){
  int n = idx / Kpad;
  int k = idx - n * Kpad;
  float v = 0.f;
  if (n < Nc && k < K) v = ld_in(W, k * Nc + n, isf32);
  Wt[idx] = f2b(v);
}
__global__ void k_transpose_all(const void* W1, const void* W2, const void* Wself,
                                const void* Wrel, const void* c1W, const void* c2W){
  int idx = blockIdx.x * 256 + threadIdx.x;
  const int isf32 = g_isf32;
  if (idx < 57344){ xp_one(W1, g_W1t, idx, 500, 100, 512, isf32); return; }
  idx -= 57344;
  if (idx < 14336){ xp_one(W2,    g_W2t,    idx, 100, 100, 128, isf32); return; }
  idx -= 14336;
  if (idx < 14336){ xp_one(Wself, g_WselfT, idx, 100, 100, 128, isf32); return; }
  idx -= 14336;
  if (idx < 14336){ xp_one(Wrel,  g_WrelT,  idx, 100, 100, 128, isf32); return; }
  idx -= 14336;
  if (idx < 14336){ xp_one(c1W,   g_c1Wt,   idx, 100, 100, 128, isf32); return; }
  idx -= 14336;
  if (idx < 8192){  xp_one(c2W,   g_c2Wt,   idx, 100, 64,  128, isf32); }
}

// ---------------- degree histogram
__global__ void k_deg(const int* __restrict__ tgt){
  int e = blockIdx.x * 256 + threadIdx.x;
  if (e < NE) atomicAdd(&g_deg[tgt[e]], 1);
}

// ---------------- two-level scan (scan1 fuses dinv)
__global__ __launch_bounds__(256) void k_scan1(){
  __shared__ int sh[256];
  int t = threadIdx.x;
  int i = blockIdx.x * 256 + t;
  int val = (i < NN) ? g_deg[i] : 0;
  sh[t] = val;
  __syncthreads();
#pragma unroll
  for (int off = 1; off < 256; off <<= 1){
    int v = (t >= off) ? sh[t - off] : 0;
    __syncthreads();
    sh[t] += v;
    __syncthreads();
  }
  if (i < NN){
    g_rowptr[i] = sh[t] - val;
    g_dinv[i] = rsqrtf((float)(val + 1));
  }
  if (t == 255) g_partial[blockIdx.x] = sh[255];
}
__global__ __launch_bounds__(256) void k_scan2(){
  __shared__ int sh[256];
  int t = threadIdx.x;
  int val = (t < SCAN_B) ? g_partial[t] : 0;
  sh[t] = val;
  __syncthreads();
#pragma unroll
  for (int off = 1; off < 256; off <<= 1){
    int v = (t >= off) ? sh[t - off] : 0;
    __syncthreads();
    sh[t] += v;
    __syncthreads();
  }
  if (t < SCAN_B) g_partial[t] = sh[t] - val;
  if (t == 255) g_rowptr[NN] = sh[255];
}
__global__ __launch_bounds__(256) void k_scan3(){
  int i = blockIdx.x * 256 + threadIdx.x;
  if (i < NN) g_rowptr[i] += g_partial[blockIdx.x];
}

// ---------------- CSR fill
__global__ void k_fill(const int* __restrict__ src, const int* __restrict__ tgt){
  int e = blockIdx.x * 256 + threadIdx.x;
  if (e >= NE) return;
  int t = tgt[e];
  int pos = g_rowptr[t] + atomicAdd(&g_cursor[t], 1);
  g_colidx[pos] = src[e];
}

// ---------------- gather-aggregate, high-MLP (16 lanes/node, x4 unroll)
template<int MODE>
__global__ __launch_bounds__(256) void k_agg(){
  const unsigned short* x = (MODE == 1) ? g_bufC : g_bufB;
  int node = blockIdx.x * 16 + (threadIdx.x >> 4);
  if (node >= NN) return;
  const int c8 = (threadIdx.x & 15) * 8;

  float wt = (MODE != 0) ? g_dinv[node] : 1.f;
  float a[4][8];
#pragma unroll
  for (int j = 0; j < 4; j++)
#pragma unroll
    for (int k = 0; k < 8; k++) a[j][k] = 0.f;

  int p0 = g_rowptr[node], p1 = g_rowptr[node + 1];
  for (int p = p0; p < p1; p += 4){
    int   sj[4]; float wj[4];
#pragma unroll
    for (int j = 0; j < 4; j++){
      bool ok = (p + j) < p1;
      sj[j] = ok ? g_colidx[p + j] : node;
      wj[j] = ok ? ((MODE != 0) ? g_dinv[sj[j]] * wt : 1.f) : 0.f;
    }
    ushort8 r[4];
#pragma unroll
    for (int j = 0; j < 4; j++)
      r[j] = *reinterpret_cast<const ushort8*>(&x[(size_t)sj[j] * 128 + c8]);
#pragma unroll
    for (int j = 0; j < 4; j++)
#pragma unroll
      for (int k = 0; k < 8; k++) a[j][k] += wj[j] * b2f((unsigned short)r[j][k]);
  }
  if (MODE != 0){
    float ws = wt * wt;
    ushort8 sv = *reinterpret_cast<const ushort8*>(&x[(size_t)node * 128 + c8]);
#pragma unroll
    for (int k = 0; k < 8; k++) a[0][k] += ws * b2f((unsigned short)sv[k]);
  }
  ushort8 o;
#pragma unroll
  for (int k = 0; k < 8; k++)
    o[k] = f2b(a[0][k] + a[1][k] + a[2][k] + a[3][k]);
  *reinterpret_cast<ushort8*>(&g_bufA[(size_t)node * 128 + c8]) = o;
}

// ---------------- GEMM1 (data_x [N,500] -> bufA): register-prefetched,
// LDS double-buffered pipeline. Per chunk: 8 independent 16B global loads
// burst into registers (8x MLP), ds_write to alternating buffer, one barrier,
// next chunk's burst issued BEFORE the MFMA phase so loads fly over compute.
__device__ __forceinline__ void g1_load(const void* Aext, int rowblk, int srow,
                                        int scol, int kc, int isf32, ushort4* vb){
  const int gcol = kc * 128 + scol;
  const bool colok = (gcol + 4 <= 500);   // 500 % 4 == 0: all-or-nothing
  if (isf32){
    f32x4 fv[8];
#pragma unroll
    for (int ps = 0; ps < 8; ps++){       // 8 independent loads, no consumers between
      int grow = rowblk + ps * 8 + srow;
      f32x4 z = {0.f, 0.f, 0.f, 0.f};
      fv[ps] = (grow < NN && colok)
             ? *reinterpret_cast<const f32x4*>((const float*)Aext + (size_t)grow * 500 + gcol)
             : z;
    }
#pragma unroll
    for (int ps = 0; ps < 8; ps++){
      vb[ps].x = f2b(fv[ps][0]); vb[ps].y = f2b(fv[ps][1]);
      vb[ps].z = f2b(fv[ps][2]); vb[ps].w = f2b(fv[ps][3]);
    }
  } else {
#pragma unroll
    for (int ps = 0; ps < 8; ps++){
      int grow = rowblk + ps * 8 + srow;
      ushort4 z = {0, 0, 0, 0};
      vb[ps] = (grow < NN && colok)
             ? *reinterpret_cast<const ushort4*>((const unsigned short*)Aext + (size_t)grow * 500 + gcol)
             : z;
    }
  }
}

__global__ __launch_bounds__(256) void k_gemm1_ln(const void* __restrict__ Aext,
    const void* __restrict__ bias, const void* __restrict__ gamma,
    const void* __restrict__ beta){
  __shared__ unsigned short sA[2][64 * 136];
  const int tid = threadIdx.x;
  const int wave = tid >> 6, lane = tid & 63;
  const int m = lane & 15, q = lane >> 4;
  const int rowblk = blockIdx.x * 64;
  const int isf32 = g_isf32;
  const int srow = tid >> 5;        // 0..7
  const int scol = (tid & 31) * 4;  // col offset within 128-wide chunk
  f32x4 acc[7] = {};
  ushort4 vb[8];

  g1_load(Aext, rowblk, srow, scol, 0, isf32, vb);

  for (int kc = 0; kc < 4; kc++){
    unsigned short* sbuf = sA[kc & 1];
#pragma unroll
    for (int ps = 0; ps < 8; ps++)
      *reinterpret_cast<ushort4*>(&sbuf[(ps * 8 + srow) * 136 + scol]) = vb[ps];
    __syncthreads();
    if (kc < 3) g1_load(Aext, rowblk, srow, scol, kc + 1, isf32, vb);  // flies over MFMA
#pragma unroll
    for (int c = 0; c < 4; c++){
      int k0 = c * 32 + q * 8;
      short8 a = *reinterpret_cast<const short8*>(&sbuf[(wave * 16 + m) * 136 + k0]);
      int gk0 = kc * 128 + k0;
#pragma unroll
      for (int t = 0; t < 7; t++){
        short8 b = *reinterpret_cast<const short8*>(g_W1t + (size_t)(t * 16 + m) * 512 + gk0);
        acc[t] = MFMA16x16x32(a, b, acc[t], 0, 0, 0);
      }
    }
    // next iteration writes the OTHER buffer; reads of this one complete
    // before each wave reaches the next barrier -> one barrier per chunk.
  }

  // epilogue: +bias, LN over 100 cols, ReLU -> g_bufA [N,128]
  float bf_[7], gf_[7], ef_[7];
#pragma unroll
  for (int t = 0; t < 7; t++){
    int col = t * 16 + m;
    bool ok = col < 100;
    bf_[t] = ok ? ld_in(bias, col, isf32)  : 0.f;
    gf_[t] = ok ? ld_in(gamma, col, isf32) : 0.f;
    ef_[t] = ok ? ld_in(beta, col, isf32)  : 0.f;
  }
  const int row0 = rowblk + wave * 16;
#pragma unroll
  for (int r = 0; r < 4; r++){
    float vals[7], s1 = 0.f, s2 = 0.f;
#pragma unroll
    for (int t = 0; t < 7; t++){
      int col = t * 16 + m;
      float v = (col < 100) ? (acc[t][r] + bf_[t]) : 0.f;
      vals[t] = v; s1 += v; s2 += v * v;
    }
#pragma unroll
    for (int msk = 1; msk < 16; msk <<= 1){
      s1 += __shfl_xor(s1, msk, 64);
      s2 += __shfl_xor(s2, msk, 64);
    }
    float mu = s1 * 0.01f;
    float var = fmaxf(s2 * 0.01f - mu * mu, 0.f);
    float rstd = rsqrtf(var + 1e-5f);
    int row = row0 + q * 4 + r;
    if (row < NN){
      unsigned short* orow = g_bufA + (size_t)row * 128;
#pragma unroll
      for (int t = 0; t < 7; t++){
        int col = t * 16 + m;
        float y = fmaxf((vals[t] - mu) * rstd * gf_[t] + ef_[t], 0.f);
        orow[col] = f2b((col < 100) ? y : 0.f);
      }
      orow[112 + m] = 0;
    }
  }
}

// ---------------- GEMM2 + LN + ReLU (bufA [N,128] @ W2t -> bufB)
__global__ __launch_bounds__(256) void k_gemm2_ln(const void* __restrict__ bias,
    const void* __restrict__ gamma, const void* __restrict__ beta){
  const int isf32 = g_isf32;
  const int wave = threadIdx.x >> 6, lane = threadIdx.x & 63;
  const int m = lane & 15, q = lane >> 4;
  const int row0 = (blockIdx.x * 4 + wave) * 16;
  if (row0 >= NN) return;
  f32x4 acc[7] = {};
  const unsigned short* arow = g_bufA + (size_t)(row0 + m) * 128;
#pragma unroll
  for (int c = 0; c < 4; c++){
    const int k0 = c * 32 + q * 8;
    short8 a = *reinterpret_cast<const short8*>(arow + k0);
#pragma unroll
    for (int t = 0; t < 7; t++){
      short8 b = *reinterpret_cast<const short8*>(g_W2t + (size_t)(t * 16 + m) * 128 + k0);
      acc[t] = MFMA16x16x32(a, b, acc[t], 0, 0, 0);
    }
  }
  float bf_[7], gf_[7], ef_[7];
#pragma unroll
  for (int t = 0; t < 7; t++){
    int col = t * 16 + m;
    bool ok = col < 100;
    bf_[t] = ok ? ld_in(bias, col, isf32)  : 0.f;
    gf_[t] = ok ? ld_in(gamma, col, isf32) : 0.f;
    ef_[t] = ok ? ld_in(beta, col, isf32)  : 0.f;
  }
#pragma unroll
  for (int r = 0; r < 4; r++){
    float vals[7], s1 = 0.f, s2 = 0.f;
#pragma unroll
    for (int t = 0; t < 7; t++){
      int col = t * 16 + m;
      float v = (col < 100) ? (acc[t][r] + bf_[t]) : 0.f;
      vals[t] = v; s1 += v; s2 += v * v;
    }
#pragma unroll
    for (int msk = 1; msk < 16; msk <<= 1){
      s1 += __shfl_xor(s1, msk, 64);
      s2 += __shfl_xor(s2, msk, 64);
    }
    float mu = s1 * 0.01f;
    float var = fmaxf(s2 * 0.01f - mu * mu, 0.f);
    float rstd = rsqrtf(var + 1e-5f);
    unsigned short* orow = g_bufB + (size_t)(row0 + q * 4 + r) * 128;
#pragma unroll
    for (int t = 0; t < 7; t++){
      int col = t * 16 + m;
      float y = fmaxf((vals[t] - mu) * rstd * gf_[t] + ef_[t], 0.f);
      orow[col] = f2b((col < 100) ? y : 0.f);
    }
    orow[112 + m] = 0;
  }
}

// ---------------- (A1@B1t [+ A2@B2t]) + bias, ReLU. K=128.
template<int SEL>
__global__ __launch_bounds__(256) void k_gemm_bias_relu(const void* __restrict__ bias){
  const unsigned short* A1  = (SEL == 0) ? g_bufB : g_bufA;
  const unsigned short* B1t = (SEL == 0) ? g_WselfT : g_c1Wt;
  unsigned short* out       = (SEL == 0) ? g_bufC : g_bufB;
  const int isf32 = g_isf32;

  const int wave = threadIdx.x >> 6, lane = threadIdx.x & 63;
  const int m = lane & 15, q = lane >> 4;
  const int row0 = (blockIdx.x * 4 + wave) * 16;
  if (row0 >= NN) return;
  f32x4 acc[7] = {};
  const unsigned short* a1row = A1 + (size_t)(row0 + m) * 128;
#pragma unroll
  for (int c = 0; c < 4; c++){
    const int k0 = c * 32 + q * 8;
    short8 a = *reinterpret_cast<const short8*>(a1row + k0);
#pragma unroll
    for (int t = 0; t < 7; t++){
      short8 b = *reinterpret_cast<const short8*>(B1t + (size_t)(t * 16 + m) * 128 + k0);
      acc[t] = MFMA16x16x32(a, b, acc[t], 0, 0, 0);
    }
  }
  if (SEL == 0){
    const unsigned short* a2row = g_bufA + (size_t)(row0 + m) * 128;
#pragma unroll
    for (int c = 0; c < 4; c++){
      const int k0 = c * 32 + q * 8;
      short8 a = *reinterpret_cast<const short8*>(a2row + k0);
#pragma unroll
      for (int t = 0; t < 7; t++){
        short8 b = *reinterpret_cast<const short8*>(g_WrelT + (size_t)(t * 16 + m) * 128 + k0);
        acc[t] = MFMA16x16x32(a, b, acc[t], 0, 0, 0);
      }
    }
  }
  float bf_[7];
#pragma unroll
  for (int t = 0; t < 7; t++){
    int col = t * 16 + m;
    bf_[t] = (col < 100) ? ld_in(bias, col, isf32) : 0.f;
  }
#pragma unroll
  for (int r = 0; r < 4; r++){
    unsigned short* orow = out + (size_t)(row0 + q * 4 + r) * 128;
#pragma unroll
    for (int t = 0; t < 7; t++){
      int col = t * 16 + m;
      float y = fmaxf(acc[t][r] + bf_[t], 0.f);
      orow[col] = f2b((col < 100) ? y : 0.f);
    }
    orow[112 + m] = 0;
  }
}

// ---------------- bufA@c2Wt + bias -> log_softmax -> d_out [N,64]
__global__ __launch_bounds__(256) void k_gemm_lsm(const void* __restrict__ bias,
                                                  void* __restrict__ outv){
  const int isf32 = g_isf32;
  const int wave = threadIdx.x >> 6, lane = threadIdx.x & 63;
  const int m = lane & 15, q = lane >> 4;
  const int row0 = (blockIdx.x * 4 + wave) * 16;
  if (row0 >= NN) return;
  f32x4 acc[4] = {};
  const unsigned short* arow = g_bufA + (size_t)(row0 + m) * 128;
#pragma unroll
  for (int c = 0; c < 4; c++){
    const int k0 = c * 32 + q * 8;
    short8 a = *reinterpret_cast<const short8*>(arow + k0);
#pragma unroll
    for (int t = 0; t < 4; t++){
      short8 b = *reinterpret_cast<const short8*>(g_c2Wt + (size_t)(t * 16 + m) * 128 + k0);
      acc[t] = MFMA16x16x32(a, b, acc[t], 0, 0, 0);
    }
  }
  float bf_[4];
#pragma unroll
  for (int t = 0; t < 4; t++) bf_[t] = ld_in(bias, t * 16 + m, isf32);
#pragma unroll
  for (int r = 0; r < 4; r++){
    float vals[4], mx = -1e30f;
#pragma unroll
    for (int t = 0; t < 4; t++){
      float v = acc[t][r] + bf_[t];
      vals[t] = v; mx = fmaxf(mx, v);
    }
#pragma unroll
    for (int msk = 1; msk < 16; msk <<= 1) mx = fmaxf(mx, __shfl_xor(mx, msk, 64));
    float se = 0.f;
#pragma unroll
    for (int t = 0; t < 4; t++) se += expf(vals[t] - mx);
#pragma unroll
    for (int msk = 1; msk < 16; msk <<= 1) se += __shfl_xor(se, msk, 64);
    float lse = logf(se);
    size_t ro = (size_t)(row0 + q * 4 + r) * 64;
    if (isf32){
      float* orow = (float*)outv + ro;
#pragma unroll
      for (int t = 0; t < 4; t++) orow[t * 16 + m] = vals[t] - mx - lse;
    } else {
      unsigned short* orow = (unsigned short*)outv + ro;
#pragma unroll
      for (int t = 0; t < 4; t++) orow[t * 16 + m] = f2b(vals[t] - mx - lse);
    }
  }
}

extern "C" void kernel_launch(void* const* d_in, const int* in_sizes, int n_in,
                              void* d_out, int out_size, void* d_ws, size_t ws_size,
                              hipStream_t stream){
  (void)in_sizes; (void)n_in; (void)out_size; (void)d_ws; (void)ws_size;
  const void* data_x = d_in[0];
  const int* ei = (const int*)d_in[1];
  const int* src = ei;
  const int* tgt = ei + NE;
  const void *W1 = d_in[3], *b1 = d_in[4], *gm1 = d_in[5], *be1 = d_in[6];
  const void *W2 = d_in[7], *b2 = d_in[8], *gm2 = d_in[9], *be2 = d_in[10];
  const void *Wrel = d_in[11], *Wself = d_in[12], *rb = d_in[13];
  const void *c1W = d_in[14], *c1b = d_in[15];
  const void *c2W = d_in[16], *c2b = d_in[17];

  k_detect<<<1, 256, 0, stream>>>((const unsigned short*)data_x);
  k_zero<<<(NN + 255) / 256, 256, 0, stream>>>();
  k_transpose_all<<<(122880 + 255) / 256, 256, 0, stream>>>(W1, W2, Wself, Wrel, c1W, c2W);

  k_deg<<<(NE + 255) / 256, 256, 0, stream>>>(tgt);
  k_scan1<<<SCAN_B, 256, 0, stream>>>();
  k_scan2<<<1, 256, 0, stream>>>();
  k_scan3<<<SCAN_B, 256, 0, stream>>>();
  k_fill<<<(NE + 255) / 256, 256, 0, stream>>>(src, tgt);

  const int G64 = (NN + 63) / 64;     // 782 blocks, 64 rows each
  const int GA  = (NN + 15) / 16;     // 3125 blocks, 16 nodes/block
  k_gemm1_ln<<<G64, 256, 0, stream>>>(data_x, b1, gm1, be1);   // data_x -> bufA
  k_gemm2_ln<<<G64, 256, 0, stream>>>(b2, gm2, be2);           // bufA -> bufB
  k_agg<0><<<GA, 256, 0, stream>>>();                          // bufB -> bufA (RGCN sum)
  k_gemm_bias_relu<0><<<G64, 256, 0, stream>>>(rb);            // bufB@Wself + bufA@Wrel -> bufC
  k_agg<1><<<GA, 256, 0, stream>>>();                          // bufC -> bufA (GCN norm)
  k_gemm_bias_relu<1><<<G64, 256, 0, stream>>>(c1b);           // bufA@c1W -> bufB
  k_agg<2><<<GA, 256, 0, stream>>>();                          // bufB -> bufA (GCN norm)
  k_gemm_lsm<<<G64, 256, 0, stream>>>(c2b, d_out);
}

// Round 8
// 520.849 us; speedup vs baseline: 1.3752x; 1.0058x over previous
//
#include <hip/hip_runtime.h>
#include <hip/hip_bf16.h>

typedef __attribute__((ext_vector_type(8))) short short8;
typedef __attribute__((ext_vector_type(8))) unsigned short ushort8;
typedef __attribute__((ext_vector_type(4))) float f32x4;

static constexpr int NN = 50000;   // nodes
static constexpr int NE = 800000;  // edges
static constexpr int SCAN_B = 196; // ceil(NN/256)

#define MFMA16x16x32 __builtin_amdgcn_mfma_f32_16x16x32_bf16

__device__ __forceinline__ float b2f(unsigned short u){
  unsigned v = ((unsigned)u) << 16;
  return __builtin_bit_cast(float, v);
}
__device__ __forceinline__ unsigned short f2b(float f){
  unsigned x = __builtin_bit_cast(unsigned, f);
  unsigned r = (x + 0x7fffu + ((x >> 16) & 1u)) >> 16;  // RNE
  return (unsigned short)r;
}

// ---------------- static device scratch
__device__ __align__(256) int   g_isf32;
__device__ __align__(256) unsigned short g_W1t  [112 * 512];
__device__ __align__(256) unsigned short g_W2t  [112 * 128];
__device__ __align__(256) unsigned short g_WselfT[112 * 128];
__device__ __align__(256) unsigned short g_WrelT [112 * 128];
__device__ __align__(256) unsigned short g_c1Wt [112 * 128];
__device__ __align__(256) unsigned short g_c2Wt [64 * 128];
__device__ __align__(256) unsigned short g_bufA[(size_t)NN * 128];
__device__ __align__(256) unsigned short g_bufB[(size_t)NN * 128];
__device__ __align__(256) unsigned short g_bufC[(size_t)NN * 128];
__device__ __align__(256) int   g_deg[NN];
__device__ __align__(256) int   g_rowptr[NN + 1];
__device__ __align__(256) int   g_cursor[NN];
__device__ __align__(256) int   g_colidx[NE];
__device__ __align__(256) float g_dinv[NN];
__device__ __align__(256) int   g_partial[256];

__device__ __forceinline__ float ld_in(const void* p, int idx, int isf32){
  if (isf32) return ((const float*)p)[idx];
  return b2f(((const unsigned short*)p)[idx]);
}

// ---------------- dtype sniffer
__global__ void k_detect(const unsigned short* __restrict__ x){
  __shared__ int sh[256];
  int tid = threadIdx.x;
  int cnt = 0;
  for (int j = 0; j < 16; j++){
    unsigned short h = x[(size_t)(tid * 16 + j) * 2];
    int e = (h >> 7) & 0xFF;
    if (e >= 90 && e <= 160) cnt++;
  }
  sh[tid] = cnt;
  __syncthreads();
  for (int off = 128; off > 0; off >>= 1){
    if (tid < off) sh[tid] += sh[tid + off];
    __syncthreads();
  }
  if (tid == 0) g_isf32 = (sh[0] < 2458) ? 1 : 0;
}

// ---------------- zero deg/cursor
__global__ void k_zero(){
  int i = blockIdx.x * 256 + threadIdx.x;
  if (i < NN){ g_deg[i] = 0; g_cursor[i] = 0; }
}

// ---------------- all 6 weight transposes in ONE launch
__device__ __forceinline__ void xp_one(const void* W, unsigned short* Wt, int idx,
                                       int K, int Nc, int Kpad, int isf32){
  int n = idx / Kpad;
  int k = idx - n * Kpad;
  float v = 0.f;
  if (n < Nc && k < K) v = ld_in(W, k * Nc + n, isf32);
  Wt[idx] = f2b(v);
}
__global__ void k_transpose_all(const void* W1, const void* W2, const void* Wself,
                                const void* Wrel, const void* c1W, const void* c2W){
  int idx = blockIdx.x * 256 + threadIdx.x;
  const int isf32 = g_isf32;
  if (idx < 57344){ xp_one(W1, g_W1t, idx, 500, 100, 512, isf32); return; }
  idx -= 57344;
  if (idx < 14336){ xp_one(W2,    g_W2t,    idx, 100, 100, 128, isf32); return; }
  idx -= 14336;
  if (idx < 14336){ xp_one(Wself, g_WselfT, idx, 100, 100, 128, isf32); return; }
  idx -= 14336;
  if (idx < 14336){ xp_one(Wrel,  g_WrelT,  idx, 100, 100, 128, isf32); return; }
  idx -= 14336;
  if (idx < 14336){ xp_one(c1W,   g_c1Wt,   idx, 100, 100, 128, isf32); return; }
  idx -= 14336;
  if (idx < 8192){  xp_one(c2W,   g_c2Wt,   idx, 100, 64,  128, isf32); }
}

// ---------------- degree histogram
__global__ void k_deg(const int* __restrict__ tgt){
  int e = blockIdx.x * 256 + threadIdx.x;
  if (e < NE) atomicAdd(&g_deg[tgt[e]], 1);
}

// ---------------- two-level scan (scan1 fuses dinv)
__global__ __launch_bounds__(256) void k_scan1(){
  __shared__ int sh[256];
  int t = threadIdx.x;
  int i = blockIdx.x * 256 + t;
  int val = (i < NN) ? g_deg[i] : 0;
  sh[t] = val;
  __syncthreads();
#pragma unroll
  for (int off = 1; off < 256; off <<= 1){
    int v = (t >= off) ? sh[t - off] : 0;
    __syncthreads();
    sh[t] += v;
    __syncthreads();
  }
  if (i < NN){
    g_rowptr[i] = sh[t] - val;
    g_dinv[i] = rsqrtf((float)(val + 1));
  }
  if (t == 255) g_partial[blockIdx.x] = sh[255];
}
__global__ __launch_bounds__(256) void k_scan2(){
  __shared__ int sh[256];
  int t = threadIdx.x;
  int val = (t < SCAN_B) ? g_partial[t] : 0;
  sh[t] = val;
  __syncthreads();
#pragma unroll
  for (int off = 1; off < 256; off <<= 1){
    int v = (t >= off) ? sh[t - off] : 0;
    __syncthreads();
    sh[t] += v;
    __syncthreads();
  }
  if (t < SCAN_B) g_partial[t] = sh[t] - val;
  if (t == 255) g_rowptr[NN] = sh[255];
}
__global__ __launch_bounds__(256) void k_scan3(){
  int i = blockIdx.x * 256 + threadIdx.x;
  if (i < NN) g_rowptr[i] += g_partial[blockIdx.x];
}

// ---------------- CSR fill
__global__ void k_fill(const int* __restrict__ src, const int* __restrict__ tgt){
  int e = blockIdx.x * 256 + threadIdx.x;
  if (e >= NE) return;
  int t = tgt[e];
  int pos = g_rowptr[t] + atomicAdd(&g_cursor[t], 1);
  g_colidx[pos] = src[e];
}

// ---------------- gather-aggregate, high-MLP (16 lanes/node, x4 unroll)
template<int MODE>
__global__ __launch_bounds__(256) void k_agg(){
  const unsigned short* x = (MODE == 1) ? g_bufC : g_bufB;
  int node = blockIdx.x * 16 + (threadIdx.x >> 4);
  if (node >= NN) return;
  const int c8 = (threadIdx.x & 15) * 8;

  float wt = (MODE != 0) ? g_dinv[node] : 1.f;
  float a[4][8];
#pragma unroll
  for (int j = 0; j < 4; j++)
#pragma unroll
    for (int k = 0; k < 8; k++) a[j][k] = 0.f;

  int p0 = g_rowptr[node], p1 = g_rowptr[node + 1];
  for (int p = p0; p < p1; p += 4){
    int   sj[4]; float wj[4];
#pragma unroll
    for (int j = 0; j < 4; j++){
      bool ok = (p + j) < p1;
      sj[j] = ok ? g_colidx[p + j] : node;
      wj[j] = ok ? ((MODE != 0) ? g_dinv[sj[j]] * wt : 1.f) : 0.f;
    }
    ushort8 r[4];
#pragma unroll
    for (int j = 0; j < 4; j++)
      r[j] = *reinterpret_cast<const ushort8*>(&x[(size_t)sj[j] * 128 + c8]);
#pragma unroll
    for (int j = 0; j < 4; j++)
#pragma unroll
      for (int k = 0; k < 8; k++) a[j][k] += wj[j] * b2f((unsigned short)r[j][k]);
  }
  if (MODE != 0){
    float ws = wt * wt;
    ushort8 sv = *reinterpret_cast<const ushort8*>(&x[(size_t)node * 128 + c8]);
#pragma unroll
    for (int k = 0; k < 8; k++) a[0][k] += ws * b2f((unsigned short)sv[k]);
  }
  ushort8 o;
#pragma unroll
  for (int k = 0; k < 8; k++)
    o[k] = f2b(a[0][k] + a[1][k] + a[2][k] + a[3][k]);
  *reinterpret_cast<ushort8*>(&g_bufA[(size_t)node * 128 + c8]) = o;
}

// ---------------- GEMM1 (data_x [N,500] -> bufA): single-wave blocks,
// no LDS, no barriers. 3125 blocks x 64 threads, 16 rows/wave (3125*16 =
// 50000 exact). Lane loads its A-fragment directly in MFMA layout,
// register double-buffered over 16 K-chunks -> independent waves keep the
// memory pipe full without barrier coupling. __launch_bounds__(64,1)
// frees VGPRs so the prefetch actually stays in flight.
// K-tail: load offset clamped to 496 (16B-aligned, always in-bounds);
// clamped values are finite and hit W1t's zero-pad -> contribute 0.
__global__ __launch_bounds__(64, 1) void k_gemm1_ln(const void* __restrict__ Aext,
    const void* __restrict__ bias, const void* __restrict__ gamma,
    const void* __restrict__ beta){
  const int lane = threadIdx.x;
  const int m = lane & 15, q = lane >> 4;
  const int row0 = blockIdx.x * 16;
  const int isf32 = g_isf32;
  f32x4 acc[7] = {};

  if (isf32){
    const float* arow = (const float*)Aext + (size_t)(row0 + m) * 500;
    const int kq = q * 8;
    f32x4 lo = *reinterpret_cast<const f32x4*>(arow + min(kq, 496));
    f32x4 hi = *reinterpret_cast<const f32x4*>(arow + min(kq + 4, 496));
#pragma unroll
    for (int c = 0; c < 16; c++){
      f32x4 lo2 = lo, hi2 = hi;
      if (c < 15){
        int kn = (c + 1) * 32 + kq;
        lo2 = *reinterpret_cast<const f32x4*>(arow + min(kn, 496));
        hi2 = *reinterpret_cast<const f32x4*>(arow + min(kn + 4, 496));
      }
      short8 a = {(short)f2b(lo[0]), (short)f2b(lo[1]), (short)f2b(lo[2]), (short)f2b(lo[3]),
                  (short)f2b(hi[0]), (short)f2b(hi[1]), (short)f2b(hi[2]), (short)f2b(hi[3])};
      const int k0 = c * 32 + kq;
#pragma unroll
      for (int t = 0; t < 7; t++){
        short8 b = *reinterpret_cast<const short8*>(g_W1t + (size_t)(t * 16 + m) * 512 + k0);
        acc[t] = MFMA16x16x32(a, b, acc[t], 0, 0, 0);
      }
      lo = lo2; hi = hi2;
    }
  } else {
    const unsigned short* arow = (const unsigned short*)Aext + (size_t)(row0 + m) * 500;
    const int kq = q * 8;
    ushort4 lo = *reinterpret_cast<const ushort4*>(arow + min(kq, 496));
    ushort4 hi = *reinterpret_cast<const ushort4*>(arow + min(kq + 4, 496));
#pragma unroll
    for (int c = 0; c < 16; c++){
      ushort4 lo2 = lo, hi2 = hi;
      if (c < 15){
        int kn = (c + 1) * 32 + kq;
        lo2 = *reinterpret_cast<const ushort4*>(arow + min(kn, 496));
        hi2 = *reinterpret_cast<const ushort4*>(arow + min(kn + 4, 496));
      }
      short8 a = {(short)lo.x, (short)lo.y, (short)lo.z, (short)lo.w,
                  (short)hi.x, (short)hi.y, (short)hi.z, (short)hi.w};
      const int k0 = c * 32 + kq;
#pragma unroll
      for (int t = 0; t < 7; t++){
        short8 b = *reinterpret_cast<const short8*>(g_W1t + (size_t)(t * 16 + m) * 512 + k0);
        acc[t] = MFMA16x16x32(a, b, acc[t], 0, 0, 0);
      }
      lo = lo2; hi = hi2;
    }
  }

  // epilogue: +bias, LN over 100 cols, ReLU -> g_bufA [N,128]
  float bf_[7], gf_[7], ef_[7];
#pragma unroll
  for (int t = 0; t < 7; t++){
    int col = t * 16 + m;
    bool ok = col < 100;
    bf_[t] = ok ? ld_in(bias, col, isf32)  : 0.f;
    gf_[t] = ok ? ld_in(gamma, col, isf32) : 0.f;
    ef_[t] = ok ? ld_in(beta, col, isf32)  : 0.f;
  }
#pragma unroll
  for (int r = 0; r < 4; r++){
    float vals[7], s1 = 0.f, s2 = 0.f;
#pragma unroll
    for (int t = 0; t < 7; t++){
      int col = t * 16 + m;
      float v = (col < 100) ? (acc[t][r] + bf_[t]) : 0.f;
      vals[t] = v; s1 += v; s2 += v * v;
    }
#pragma unroll
    for (int msk = 1; msk < 16; msk <<= 1){
      s1 += __shfl_xor(s1, msk, 64);
      s2 += __shfl_xor(s2, msk, 64);
    }
    float mu = s1 * 0.01f;
    float var = fmaxf(s2 * 0.01f - mu * mu, 0.f);
    float rstd = rsqrtf(var + 1e-5f);
    unsigned short* orow = g_bufA + (size_t)(row0 + q * 4 + r) * 128;
#pragma unroll
    for (int t = 0; t < 7; t++){
      int col = t * 16 + m;
      float y = fmaxf((vals[t] - mu) * rstd * gf_[t] + ef_[t], 0.f);
      orow[col] = f2b((col < 100) ? y : 0.f);
    }
    orow[112 + m] = 0;
  }
}

// ---------------- GEMM2 + LN + ReLU (bufA [N,128] @ W2t -> bufB)
__global__ __launch_bounds__(256) void k_gemm2_ln(const void* __restrict__ bias,
    const void* __restrict__ gamma, const void* __restrict__ beta){
  const int isf32 = g_isf32;
  const int wave = threadIdx.x >> 6, lane = threadIdx.x & 63;
  const int m = lane & 15, q = lane >> 4;
  const int row0 = (blockIdx.x * 4 + wave) * 16;
  if (row0 >= NN) return;
  f32x4 acc[7] = {};
  const unsigned short* arow = g_bufA + (size_t)(row0 + m) * 128;
#pragma unroll
  for (int c = 0; c < 4; c++){
    const int k0 = c * 32 + q * 8;
    short8 a = *reinterpret_cast<const short8*>(arow + k0);
#pragma unroll
    for (int t = 0; t < 7; t++){
      short8 b = *reinterpret_cast<const short8*>(g_W2t + (size_t)(t * 16 + m) * 128 + k0);
      acc[t] = MFMA16x16x32(a, b, acc[t], 0, 0, 0);
    }
  }
  float bf_[7], gf_[7], ef_[7];
#pragma unroll
  for (int t = 0; t < 7; t++){
    int col = t * 16 + m;
    bool ok = col < 100;
    bf_[t] = ok ? ld_in(bias, col, isf32)  : 0.f;
    gf_[t] = ok ? ld_in(gamma, col, isf32) : 0.f;
    ef_[t] = ok ? ld_in(beta, col, isf32)  : 0.f;
  }
#pragma unroll
  for (int r = 0; r < 4; r++){
    float vals[7], s1 = 0.f, s2 = 0.f;
#pragma unroll
    for (int t = 0; t < 7; t++){
      int col = t * 16 + m;
      float v = (col < 100) ? (acc[t][r] + bf_[t]) : 0.f;
      vals[t] = v; s1 += v; s2 += v * v;
    }
#pragma unroll
    for (int msk = 1; msk < 16; msk <<= 1){
      s1 += __shfl_xor(s1, msk, 64);
      s2 += __shfl_xor(s2, msk, 64);
    }
    float mu = s1 * 0.01f;
    float var = fmaxf(s2 * 0.01f - mu * mu, 0.f);
    float rstd = rsqrtf(var + 1e-5f);
    unsigned short* orow = g_bufB + (size_t)(row0 + q * 4 + r) * 128;
#pragma unroll
    for (int t = 0; t < 7; t++){
      int col = t * 16 + m;
      float y = fmaxf((vals[t] - mu) * rstd * gf_[t] + ef_[t], 0.f);
      orow[col] = f2b((col < 100) ? y : 0.f);
    }
    orow[112 + m] = 0;
  }
}

// ---------------- (A1@B1t [+ A2@B2t]) + bias, ReLU. K=128.
template<int SEL>
__global__ __launch_bounds__(256) void k_gemm_bias_relu(const void* __restrict__ bias){
  const unsigned short* A1  = (SEL == 0) ? g_bufB : g_bufA;
  const unsigned short* B1t = (SEL == 0) ? g_WselfT : g_c1Wt;
  unsigned short* out       = (SEL == 0) ? g_bufC : g_bufB;
  const int isf32 = g_isf32;

  const int wave = threadIdx.x >> 6, lane = threadIdx.x & 63;
  const int m = lane & 15, q = lane >> 4;
  const int row0 = (blockIdx.x * 4 + wave) * 16;
  if (row0 >= NN) return;
  f32x4 acc[7] = {};
  const unsigned short* a1row = A1 + (size_t)(row0 + m) * 128;
#pragma unroll
  for (int c = 0; c < 4; c++){
    const int k0 = c * 32 + q * 8;
    short8 a = *reinterpret_cast<const short8*>(a1row + k0);
#pragma unroll
    for (int t = 0; t < 7; t++){
      short8 b = *reinterpret_cast<const short8*>(B1t + (size_t)(t * 16 + m) * 128 + k0);
      acc[t] = MFMA16x16x32(a, b, acc[t], 0, 0, 0);
    }
  }
  if (SEL == 0){
    const unsigned short* a2row = g_bufA + (size_t)(row0 + m) * 128;
#pragma unroll
    for (int c = 0; c < 4; c++){
      const int k0 = c * 32 + q * 8;
      short8 a = *reinterpret_cast<const short8*>(a2row + k0);
#pragma unroll
      for (int t = 0; t < 7; t++){
        short8 b = *reinterpret_cast<const short8*>(g_WrelT + (size_t)(t * 16 + m) * 128 + k0);
        acc[t] = MFMA16x16x32(a, b, acc[t], 0, 0, 0);
      }
    }
  }
  float bf_[7];
#pragma unroll
  for (int t = 0; t < 7; t++){
    int col = t * 16 + m;
    bf_[t] = (col < 100) ? ld_in(bias, col, isf32) : 0.f;
  }
#pragma unroll
  for (int r = 0; r < 4; r++){
    unsigned short* orow = out + (size_t)(row0 + q * 4 + r) * 128;
#pragma unroll
    for (int t = 0; t < 7; t++){
      int col = t * 16 + m;
      float y = fmaxf(acc[t][r] + bf_[t], 0.f);
      orow[col] = f2b((col < 100) ? y : 0.f);
    }
    orow[112 + m] = 0;
  }
}

// ---------------- bufA@c2Wt + bias -> log_softmax -> d_out [N,64]
__global__ __launch_bounds__(256) void k_gemm_lsm(const void* __restrict__ bias,
                                                  void* __restrict__ outv){
  const int isf32 = g_isf32;
  const int wave = threadIdx.x >> 6, lane = threadIdx.x & 63;
  const int m = lane & 15, q = lane >> 4;
  const int row0 = (blockIdx.x * 4 + wave) * 16;
  if (row0 >= NN) return;
  f32x4 acc[4] = {};
  const unsigned short* arow = g_bufA + (size_t)(row0 + m) * 128;
#pragma unroll
  for (int c = 0; c < 4; c++){
    const int k0 = c * 32 + q * 8;
    short8 a = *reinterpret_cast<const short8*>(arow + k0);
#pragma unroll
    for (int t = 0; t < 4; t++){
      short8 b = *reinterpret_cast<const short8*>(g_c2Wt + (size_t)(t * 16 + m) * 128 + k0);
      acc[t] = MFMA16x16x32(a, b, acc[t], 0, 0, 0);
    }
  }
  float bf_[4];
#pragma unroll
  for (int t = 0; t < 4; t++) bf_[t] = ld_in(bias, t * 16 + m, isf32);
#pragma unroll
  for (int r = 0; r < 4; r++){
    float vals[4], mx = -1e30f;
#pragma unroll
    for (int t = 0; t < 4; t++){
      float v = acc[t][r] + bf_[t];
      vals[t] = v; mx = fmaxf(mx, v);
    }
#pragma unroll
    for (int msk = 1; msk < 16; msk <<= 1) mx = fmaxf(mx, __shfl_xor(mx, msk, 64));
    float se = 0.f;
#pragma unroll
    for (int t = 0; t < 4; t++) se += expf(vals[t] - mx);
#pragma unroll
    for (int msk = 1; msk < 16; msk <<= 1) se += __shfl_xor(se, msk, 64);
    float lse = logf(se);
    size_t ro = (size_t)(row0 + q * 4 + r) * 64;
    if (isf32){
      float* orow = (float*)outv + ro;
#pragma unroll
      for (int t = 0; t < 4; t++) orow[t * 16 + m] = vals[t] - mx - lse;
    } else {
      unsigned short* orow = (unsigned short*)outv + ro;
#pragma unroll
      for (int t = 0; t < 4; t++) orow[t * 16 + m] = f2b(vals[t] - mx - lse);
    }
  }
}

extern "C" void kernel_launch(void* const* d_in, const int* in_sizes, int n_in,
                              void* d_out, int out_size, void* d_ws, size_t ws_size,
                              hipStream_t stream){
  (void)in_sizes; (void)n_in; (void)out_size; (void)d_ws; (void)ws_size;
  const void* data_x = d_in[0];
  const int* ei = (const int*)d_in[1];
  const int* src = ei;
  const int* tgt = ei + NE;
  const void *W1 = d_in[3], *b1 = d_in[4], *gm1 = d_in[5], *be1 = d_in[6];
  const void *W2 = d_in[7], *b2 = d_in[8], *gm2 = d_in[9], *be2 = d_in[10];
  const void *Wrel = d_in[11], *Wself = d_in[12], *rb = d_in[13];
  const void *c1W = d_in[14], *c1b = d_in[15];
  const void *c2W = d_in[16], *c2b = d_in[17];

  k_detect<<<1, 256, 0, stream>>>((const unsigned short*)data_x);
  k_zero<<<(NN + 255) / 256, 256, 0, stream>>>();
  k_transpose_all<<<(122880 + 255) / 256, 256, 0, stream>>>(W1, W2, Wself, Wrel, c1W, c2W);

  k_deg<<<(NE + 255) / 256, 256, 0, stream>>>(tgt);
  k_scan1<<<SCAN_B, 256, 0, stream>>>();
  k_scan2<<<1, 256, 0, stream>>>();
  k_scan3<<<SCAN_B, 256, 0, stream>>>();
  k_fill<<<(NE + 255) / 256, 256, 0, stream>>>(src, tgt);

  const int G64 = (NN + 63) / 64;     // 782 blocks, 4 waves x 16 rows
  const int GA  = (NN + 15) / 16;     // 3125 blocks, 16 nodes/block
  k_gemm1_ln<<<3125, 64, 0, stream>>>(data_x, b1, gm1, be1);   // data_x -> bufA
  k_gemm2_ln<<<G64, 256, 0, stream>>>(b2, gm2, be2);           // bufA -> bufB
  k_agg<0><<<GA, 256, 0, stream>>>();                          // bufB -> bufA (RGCN sum)
  k_gemm_bias_relu<0><<<G64, 256, 0, stream>>>(rb);            // bufB@Wself + bufA@Wrel -> bufC
  k_agg<1><<<GA, 256, 0, stream>>>();                          // bufC -> bufA (GCN norm)
  k_gemm_bias_relu<1><<<G64, 256, 0, stream>>>(c1b);           // bufA@c1W -> bufB
  k_agg<2><<<GA, 256, 0, stream>>>();                          // bufB -> bufA (GCN norm)
  k_gemm_lsm<<<G64, 256, 0, stream>>>(c2b, d_out);
}